// Round 2
// baseline (4665.081 us; speedup 1.0000x reference)
//
#include <hip/hip_runtime.h>
#include <hip/hip_bf16.h>

typedef __hip_bfloat16 bf16;

#define N_NODES 100000
#define N_EDGES_C 1600000

// ---------- runtime dtype helpers (flags[0]=floats-are-bf16, flags[1]=indices-are-int64) ----------
__device__ __forceinline__ float ldf(const void* p, long i, int isbf) {
    return isbf ? __bfloat162float(((const bf16*)p)[i]) : ((const float*)p)[i];
}
__device__ __forceinline__ int ldidx(const int* ei, long pos, int is64) {
    // int64 little-endian: low word of element `pos` is at int32 index 2*pos
    return is64 ? ei[2 * pos] : ei[pos];
}

// Order-preserving unsigned encoding of float (monotone for all finite values).
__device__ __forceinline__ unsigned flipF(float f) {
    unsigned u = __float_as_uint(f);
    return u ^ (unsigned)(((int)u >> 31) | 0x80000000);
}
__device__ __forceinline__ float unflipF(unsigned u) {
    unsigned v = u ^ (unsigned)(((int)(~u) >> 31) | 0x80000000);
    return __uint_as_float(v);
}

// ---------- dtype detection ----------
// f32 buffer viewed as bf16: even elements come from f32 mantissa bits -> random
// exponents -> ~42% have |v|>1e6. Real bf16 N(0,1) data: none do.
// int64 indices viewed as int32: all odd words are 0 (values < 2^31). int32 data:
// odd words are random node ids, P(all 128 == 0) ~ 1e-640.
__global__ void detect_kernel(const void* emb, const int* ei, int* flags) {
    if (blockIdx.x == 0 && threadIdx.x == 0) {
        const bf16* pb = (const bf16*)emb;
        int big = 0;
        for (int i = 0; i < 256; i++) {
            float v = __bfloat162float(pb[i]);
            if (!(v > -1.0e6f && v < 1.0e6f)) big++;  // catches inf/nan too
        }
        flags[0] = (big <= 8) ? 1 : 0;   // 1 => float tensors are bf16
        int nz = 0;
        for (int i = 1; i < 256; i += 2) nz += (ei[i] != 0) ? 1 : 0;
        flags[1] = (nz == 0) ? 1 : 0;    // 1 => edge_index is int64
    }
}

__global__ void zero_f(float* __restrict__ p, int n) {
    int i = blockIdx.x * blockDim.x + threadIdx.x;
    if (i < n) p[i] = 0.0f;
}

// q,k,v,s = X @ W{q,k,v,s} + b. One thread per (node, out_col).
template <int DIN, int DOUT, bool XF32>
__global__ void node_linear(const void* __restrict__ X,
                            const void* __restrict__ Wq, const void* __restrict__ bq,
                            const void* __restrict__ Wk, const void* __restrict__ bk,
                            const void* __restrict__ Wv, const void* __restrict__ bv,
                            const void* __restrict__ Ws, const void* __restrict__ bs,
                            const int* __restrict__ flags,
                            float* __restrict__ q, float* __restrict__ k,
                            float* __restrict__ v, float* __restrict__ s) {
    const int isbf = flags[0];
    __shared__ float sW[4][DIN * DOUT];
    __shared__ float sb[4][DOUT];
    for (int i = threadIdx.x; i < DIN * DOUT; i += blockDim.x) {
        sW[0][i] = ldf(Wq, i, isbf);
        sW[1][i] = ldf(Wk, i, isbf);
        sW[2][i] = ldf(Wv, i, isbf);
        sW[3][i] = ldf(Ws, i, isbf);
    }
    if (threadIdx.x < DOUT) {
        sb[0][threadIdx.x] = ldf(bq, threadIdx.x, isbf);
        sb[1][threadIdx.x] = ldf(bk, threadIdx.x, isbf);
        sb[2][threadIdx.x] = ldf(bv, threadIdx.x, isbf);
        sb[3][threadIdx.x] = ldf(bs, threadIdx.x, isbf);
    }
    __syncthreads();
    int gid = blockIdx.x * blockDim.x + threadIdx.x;
    if (gid >= N_NODES * DOUT) return;
    int n = gid / DOUT;
    int c = gid % DOUT;
    const long base = (long)n * DIN;
    float aq = sb[0][c], ak = sb[1][c], av = sb[2][c], as_ = sb[3][c];
#pragma unroll
    for (int t = 0; t < DIN; t++) {
        float xv = XF32 ? ((const float*)X)[base + t] : ldf(X, base + t, isbf);
        aq  += xv * sW[0][t * DOUT + c];
        ak  += xv * sW[1][t * DOUT + c];
        av  += xv * sW[2][t * DOUT + c];
        as_ += xv * sW[3][t * DOUT + c];
    }
    q[gid] = aq; k[gid] = ak; v[gid] = av; s[gid] = as_;
}

// Pass A: alpha_e = dot(q[dst],k[src]) / sqrt(D); atomic seg-max into segmax[dst].
template <int D>
__global__ void edge_alpha(const int* __restrict__ ei, const int* __restrict__ flags,
                           const float* __restrict__ q, const float* __restrict__ k,
                           float* __restrict__ alpha, unsigned* __restrict__ segmax) {
    int e = blockIdx.x * blockDim.x + threadIdx.x;
    if (e >= N_EDGES_C) return;
    const int is64 = flags[1];
    int sN = ldidx(ei, e, is64);
    int dN = ldidx(ei, (long)N_EDGES_C + e, is64);
    const float* qr = q + (size_t)dN * D;
    const float* kr = k + (size_t)sN * D;
    float acc = 0.0f;
#pragma unroll
    for (int i = 0; i < D; i++) acc += qr[i] * kr[i];
    const float rsq = (D == 32) ? 0.17677669529663689f : 0.25f;  // 1/sqrt(D)
    float al = acc * rsq;
    alpha[e] = al;
    atomicMax(&segmax[dN], flipF(al));
}

// Pass B: ex = exp(alpha - segmax[dst]); segsum[dst] += ex; agg[dst] += v[src] * ex.
template <int D>
__global__ void edge_accum(const int* __restrict__ ei, const int* __restrict__ flags,
                           const float* __restrict__ alpha, const unsigned* __restrict__ segmax,
                           const float* __restrict__ v,
                           float* __restrict__ segsum, float* __restrict__ agg) {
    int e = blockIdx.x * blockDim.x + threadIdx.x;
    if (e >= N_EDGES_C) return;
    const int is64 = flags[1];
    int sN = ldidx(ei, e, is64);
    int dN = ldidx(ei, (long)N_EDGES_C + e, is64);
    float m = unflipF(segmax[dN]);
    float ex = __expf(alpha[e] - m);
    atomicAdd(&segsum[dN], ex);
    const float* vr = v + (size_t)sN * D;
    float* ar = agg + (size_t)dN * D;
#pragma unroll
    for (int c = 0; c < D; c++) atomicAdd(&ar[c], vr[c] * ex);
}

// h = relu(agg/(segsum+eps) + s), layer-1, fp32 out (internal).
__global__ void finish1(const float* __restrict__ agg, const float* __restrict__ segsum,
                        const float* __restrict__ s, float* __restrict__ h) {
    int i = blockIdx.x * blockDim.x + threadIdx.x;
    if (i >= N_NODES * 32) return;
    int n = i >> 5;
    float val = agg[i] / (segsum[n] + 1e-16f) + s[i];
    h[i] = val > 0.0f ? val : 0.0f;
}

// out = relu(agg2/(sum+eps)+s2) @ Wo + bo; output dtype follows input float policy.
__global__ void finish2_out(const float* __restrict__ agg, const float* __restrict__ segsum,
                            const float* __restrict__ s,
                            const void* __restrict__ Wo, const void* __restrict__ bo,
                            const int* __restrict__ flags, void* __restrict__ out) {
    int n = blockIdx.x * blockDim.x + threadIdx.x;
    if (n >= N_NODES) return;
    const int isbf = flags[0];
    float inv = 1.0f / (segsum[n] + 1e-16f);
    float o0 = ldf(bo, 0, isbf), o1 = ldf(bo, 1, isbf);
    const float* ar = agg + (size_t)n * 16;
    const float* sr = s + (size_t)n * 16;
#pragma unroll
    for (int c = 0; c < 16; c++) {
        float h = ar[c] * inv + sr[c];
        h = h > 0.0f ? h : 0.0f;
        o0 += h * ldf(Wo, c * 2 + 0, isbf);
        o1 += h * ldf(Wo, c * 2 + 1, isbf);
    }
    if (isbf) {
        ((bf16*)out)[n * 2 + 0] = __float2bfloat16(o0);
        ((bf16*)out)[n * 2 + 1] = __float2bfloat16(o1);
    } else {
        ((float*)out)[n * 2 + 0] = o0;
        ((float*)out)[n * 2 + 1] = o1;
    }
}

extern "C" void kernel_launch(void* const* d_in, const int* in_sizes, int n_in,
                              void* d_out, int out_size, void* d_ws, size_t ws_size,
                              hipStream_t stream) {
    const int* ei  = (const int*)d_in[0];
    const void* emb = d_in[1];
    const void *Wq1 = d_in[2],  *bq1 = d_in[3];
    const void *Wk1 = d_in[4],  *bk1 = d_in[5];
    const void *Wv1 = d_in[6],  *bv1 = d_in[7];
    const void *Ws1 = d_in[8],  *bs1 = d_in[9];
    const void *Wq2 = d_in[10], *bq2 = d_in[11];
    const void *Wk2 = d_in[12], *bk2 = d_in[13];
    const void *Wv2 = d_in[14], *bv2 = d_in[15];
    const void *Ws2 = d_in[16], *bs2 = d_in[17];
    const void *Wo  = d_in[18], *bo  = d_in[19];

    // Workspace layout (floats). flags first (256B), then arrays.
    // alpha aliases h1 (their live ranges don't overlap):
    //   L1: edge_alpha(w alpha) -> edge_accum(r alpha) -> finish1(w h1)
    //   L2: node_linear(r h1) -> edge_alpha(w alpha) -> edge_accum(r alpha)
    const size_t ND = (size_t)N_NODES * 32;
    int*   flags  = (int*)d_ws;
    float* q      = (float*)d_ws + 64;
    float* k      = q + ND;
    float* v      = k + ND;
    float* s      = v + ND;
    float* agg    = s + ND;
    float* segsum = agg + ND;
    unsigned* segmax = (unsigned*)(segsum + N_NODES);
    float* h1     = (float*)(segmax + N_NODES);  // ND floats; alpha aliases this
    float* alpha  = h1;
    // total: 6*3.2M + 0.2M + 64 floats = ~77.7 MB

    const int B = 256;
    const int zeroN   = (int)(ND + 2 * N_NODES);  // agg + segsum + segmax contiguous
    const int gZero   = (zeroN + B - 1) / B;
    const int gNode32 = (N_NODES * 32 + B - 1) / B;
    const int gNode16 = (N_NODES * 16 + B - 1) / B;
    const int gEdge   = (N_EDGES_C + B - 1) / B;
    const int gNode   = (N_NODES + B - 1) / B;

    detect_kernel<<<1, 64, 0, stream>>>(emb, ei, flags);

    // ---- Layer 1 (32 -> 32) ----
    zero_f<<<gZero, B, 0, stream>>>(agg, zeroN);
    node_linear<32, 32, false><<<gNode32, B, 0, stream>>>(
        emb, Wq1, bq1, Wk1, bk1, Wv1, bv1, Ws1, bs1, flags, q, k, v, s);
    edge_alpha<32><<<gEdge, B, 0, stream>>>(ei, flags, q, k, alpha, segmax);
    edge_accum<32><<<gEdge, B, 0, stream>>>(ei, flags, alpha, segmax, v, segsum, agg);
    finish1<<<gNode32, B, 0, stream>>>(agg, segsum, s, h1);

    // ---- Layer 2 (32 -> 16) ----
    zero_f<<<gZero, B, 0, stream>>>(agg, zeroN);
    node_linear<32, 16, true><<<gNode16, B, 0, stream>>>(
        h1, Wq2, bq2, Wk2, bk2, Wv2, bv2, Ws2, bs2, flags, q, k, v, s);
    edge_alpha<16><<<gEdge, B, 0, stream>>>(ei, flags, q, k, alpha, segmax);
    edge_accum<16><<<gEdge, B, 0, stream>>>(ei, flags, alpha, segmax, v, segsum, agg);
    finish2_out<<<gNode, B, 0, stream>>>(agg, segsum, s, Wo, bo, flags, (void*)d_out);
}

// Round 3
// 724.778 us; speedup vs baseline: 6.4366x; 6.4366x over previous
//
#include <hip/hip_runtime.h>
#include <hip/hip_bf16.h>

typedef __hip_bfloat16 bf16;

#define N_NODES 100000
#define N_EDGES_C 1600000
#define SCAN_CHUNK 512
#define N_CHUNKS ((N_NODES + SCAN_CHUNK - 1) / SCAN_CHUNK)   // 196

// ---------- runtime dtype helpers (flags[0]=floats-are-bf16, flags[1]=indices-are-int64) ----------
__device__ __forceinline__ float ldf(const void* p, long i, int isbf) {
    return isbf ? __bfloat162float(((const bf16*)p)[i]) : ((const float*)p)[i];
}
__device__ __forceinline__ int ldidx(const int* ei, long pos, int is64) {
    return is64 ? ei[2 * pos] : ei[pos];   // int64 LE: low word at 2*pos
}

// ---------- dtype detection ----------
__global__ void detect_kernel(const void* emb, const int* ei, int* flags) {
    if (blockIdx.x == 0 && threadIdx.x == 0) {
        const bf16* pb = (const bf16*)emb;
        int big = 0;
        for (int i = 0; i < 256; i++) {
            float v = __bfloat162float(pb[i]);
            if (!(v > -1.0e6f && v < 1.0e6f)) big++;  // f32-viewed-as-bf16 => ~42% huge/nan
        }
        flags[0] = (big <= 8) ? 1 : 0;
        int nz = 0;
        for (int i = 1; i < 256; i += 2) nz += (ei[i] != 0) ? 1 : 0;
        flags[1] = (nz == 0) ? 1 : 0;     // int64 => odd int32 words all zero
    }
}

__global__ void zero_i(int* __restrict__ p, int n) {
    int i = blockIdx.x * blockDim.x + threadIdx.x;
    if (i < n) p[i] = 0;
}

// ---------- CSR build ----------
__global__ void hist_deg(const int* __restrict__ ei, const int* __restrict__ flags,
                         int* __restrict__ deg) {
    int e = blockIdx.x * blockDim.x + threadIdx.x;
    if (e >= N_EDGES_C) return;
    int d = ldidx(ei, (long)N_EDGES_C + e, flags[1]);
    atomicAdd(&deg[d], 1);
}

// Per-chunk exclusive scan (chunk=512), emits chunk sums.
__global__ void scan_chunk(const int* __restrict__ deg, int* __restrict__ partial,
                           int* __restrict__ chunkSums) {
    __shared__ int tmp[SCAN_CHUNK];
    int i = blockIdx.x * SCAN_CHUNK + threadIdx.x;
    int v = (i < N_NODES) ? deg[i] : 0;
    tmp[threadIdx.x] = v;
    __syncthreads();
    for (int off = 1; off < SCAN_CHUNK; off <<= 1) {
        int t = (threadIdx.x >= off) ? tmp[threadIdx.x - off] : 0;
        __syncthreads();
        tmp[threadIdx.x] += t;
        __syncthreads();
    }
    if (i < N_NODES) partial[i] = tmp[threadIdx.x] - v;  // exclusive
    if (threadIdx.x == SCAN_CHUNK - 1) chunkSums[blockIdx.x] = tmp[threadIdx.x];
}

// Single-block exclusive scan of chunk sums (N_CHUNKS <= 256).
__global__ void scan_sums(int* __restrict__ chunkSums, int* __restrict__ chunkOffs) {
    __shared__ int tmp[256];
    int v = (threadIdx.x < N_CHUNKS) ? chunkSums[threadIdx.x] : 0;
    tmp[threadIdx.x] = v;
    __syncthreads();
    for (int off = 1; off < 256; off <<= 1) {
        int t = (threadIdx.x >= off) ? tmp[threadIdx.x - off] : 0;
        __syncthreads();
        tmp[threadIdx.x] += t;
        __syncthreads();
    }
    if (threadIdx.x < N_CHUNKS) chunkOffs[threadIdx.x] = tmp[threadIdx.x] - v;
}

__global__ void add_offs(const int* __restrict__ partial, const int* __restrict__ chunkOffs,
                         int* __restrict__ rowptr) {
    int i = blockIdx.x * blockDim.x + threadIdx.x;
    if (i < N_NODES) rowptr[i] = partial[i] + chunkOffs[i / SCAN_CHUNK];
    if (i == 0) rowptr[N_NODES] = N_EDGES_C;
}

__global__ void scatter_src(const int* __restrict__ ei, const int* __restrict__ flags,
                            const int* __restrict__ rowptr, int* __restrict__ cursor,
                            int* __restrict__ esrc) {
    int e = blockIdx.x * blockDim.x + threadIdx.x;
    if (e >= N_EDGES_C) return;
    const int is64 = flags[1];
    int s = ldidx(ei, e, is64);
    int d = ldidx(ei, (long)N_EDGES_C + e, is64);
    int pos = rowptr[d] + atomicAdd(&cursor[d], 1);
    esrc[pos] = s;
}

// ---------- node linears: q,k,v,s = X @ W{q,k,v,s} + b ----------
template <int DIN, int DOUT, bool XF32>
__global__ void node_linear(const void* __restrict__ X,
                            const void* __restrict__ Wq, const void* __restrict__ bq,
                            const void* __restrict__ Wk, const void* __restrict__ bk,
                            const void* __restrict__ Wv, const void* __restrict__ bv,
                            const void* __restrict__ Ws, const void* __restrict__ bs,
                            const int* __restrict__ flags,
                            float* __restrict__ q, float* __restrict__ k,
                            float* __restrict__ v, float* __restrict__ s) {
    const int isbf = flags[0];
    __shared__ float sW[4][DIN * DOUT];
    __shared__ float sb[4][DOUT];
    for (int i = threadIdx.x; i < DIN * DOUT; i += blockDim.x) {
        sW[0][i] = ldf(Wq, i, isbf);
        sW[1][i] = ldf(Wk, i, isbf);
        sW[2][i] = ldf(Wv, i, isbf);
        sW[3][i] = ldf(Ws, i, isbf);
    }
    if (threadIdx.x < DOUT) {
        sb[0][threadIdx.x] = ldf(bq, threadIdx.x, isbf);
        sb[1][threadIdx.x] = ldf(bk, threadIdx.x, isbf);
        sb[2][threadIdx.x] = ldf(bv, threadIdx.x, isbf);
        sb[3][threadIdx.x] = ldf(bs, threadIdx.x, isbf);
    }
    __syncthreads();
    int gid = blockIdx.x * blockDim.x + threadIdx.x;
    if (gid >= N_NODES * DOUT) return;
    int n = gid / DOUT;
    int c = gid % DOUT;
    const long base = (long)n * DIN;
    float aq = sb[0][c], ak = sb[1][c], av = sb[2][c], as_ = sb[3][c];
#pragma unroll
    for (int t = 0; t < DIN; t++) {
        float xv = XF32 ? ((const float*)X)[base + t] : ldf(X, base + t, isbf);
        aq  += xv * sW[0][t * DOUT + c];
        ak  += xv * sW[1][t * DOUT + c];
        av  += xv * sW[2][t * DOUT + c];
        as_ += xv * sW[3][t * DOUT + c];
    }
    q[gid] = aq; k[gid] = ak; v[gid] = av; s[gid] = as_;
}

// ---------- fused gather attention (one D-lane group per dst, online softmax) ----------
// LAYER2=false: writes h1[dst][c] = relu(agg/(sum+eps) + s).
// LAYER2=true : additionally folds the 16->2 output linear, writes out[dst][0..1].
template <int D, bool LAYER2>
__global__ void gather_attn(const int* __restrict__ rowptr, const int* __restrict__ esrc,
                            const float* __restrict__ q, const float* __restrict__ k,
                            const float* __restrict__ v, const float* __restrict__ s,
                            const void* __restrict__ Wo, const void* __restrict__ bo,
                            const int* __restrict__ flags,
                            float* __restrict__ h1, void* __restrict__ out) {
    const int G = 64 / D;  // dst groups per wave
    int lane = threadIdx.x & 63;
    int wave = (blockIdx.x * blockDim.x + threadIdx.x) >> 6;
    int g = lane / D;
    int c = lane % D;
    int dst = wave * G + g;
    if (dst >= N_NODES) return;  // uniform within a D-lane group; shfl stays in-group

    const float rsq = (D == 32) ? 0.17677669529663689f : 0.25f;  // 1/sqrt(D)
    float qc = q[(size_t)dst * D + c];
    int beg = rowptr[dst], end = rowptr[dst + 1];

    float m = -3.0e38f, sum = 0.0f, acc = 0.0f;
    float kc_n = 0.0f, vc_n = 0.0f;
    if (beg < end) {
        int sn = esrc[beg];
        kc_n = k[(size_t)sn * D + c];
        vc_n = v[(size_t)sn * D + c];
    }
    for (int e = beg; e < end; e++) {
        float kc = kc_n, vc = vc_n;
        if (e + 1 < end) {                 // prefetch next edge's rows
            int sn = esrc[e + 1];
            kc_n = k[(size_t)sn * D + c];
            vc_n = v[(size_t)sn * D + c];
        }
        float p = qc * kc;
#pragma unroll
        for (int mask = D / 2; mask >= 1; mask >>= 1) p += __shfl_xor(p, mask, D);
        float al = p * rsq;
        float mn = fmaxf(m, al);
        float scale = __expf(m - mn);      // first iter: exp(-inf)=0
        float ex = __expf(al - mn);
        sum = sum * scale + ex;
        acc = acc * scale + vc * ex;
        m = mn;
    }
    float h = acc / (sum + 1e-16f) + s[(size_t)dst * D + c];
    h = h > 0.0f ? h : 0.0f;

    if (!LAYER2) {
        h1[(size_t)dst * D + c] = h;
    } else {
        const int isbf = flags[0];
        float p0 = h * ldf(Wo, c * 2 + 0, isbf);
        float p1 = h * ldf(Wo, c * 2 + 1, isbf);
#pragma unroll
        for (int mask = D / 2; mask >= 1; mask >>= 1) {
            p0 += __shfl_xor(p0, mask, D);
            p1 += __shfl_xor(p1, mask, D);
        }
        if (c == 0) {
            float o0 = p0 + ldf(bo, 0, isbf);
            float o1 = p1 + ldf(bo, 1, isbf);
            if (isbf) {
                ((bf16*)out)[dst * 2 + 0] = __float2bfloat16(o0);
                ((bf16*)out)[dst * 2 + 1] = __float2bfloat16(o1);
            } else {
                ((float*)out)[dst * 2 + 0] = o0;
                ((float*)out)[dst * 2 + 1] = o1;
            }
        }
    }
}

extern "C" void kernel_launch(void* const* d_in, const int* in_sizes, int n_in,
                              void* d_out, int out_size, void* d_ws, size_t ws_size,
                              hipStream_t stream) {
    const int* ei  = (const int*)d_in[0];
    const void* emb = d_in[1];
    const void *Wq1 = d_in[2],  *bq1 = d_in[3];
    const void *Wk1 = d_in[4],  *bk1 = d_in[5];
    const void *Wv1 = d_in[6],  *bv1 = d_in[7];
    const void *Ws1 = d_in[8],  *bs1 = d_in[9];
    const void *Wq2 = d_in[10], *bq2 = d_in[11];
    const void *Wk2 = d_in[12], *bk2 = d_in[13];
    const void *Wv2 = d_in[14], *bv2 = d_in[15];
    const void *Ws2 = d_in[16], *bs2 = d_in[17];
    const void *Wo  = d_in[18], *bo  = d_in[19];

    // Workspace layout
    const size_t ND = (size_t)N_NODES * 32;
    int*   flags   = (int*)d_ws;                  // 64
    float* q       = (float*)d_ws + 64;           // ND
    float* k       = q + ND;                      // ND
    float* v       = k + ND;                      // ND
    float* s       = v + ND;                      // ND
    float* h1      = s + ND;                      // ND
    int*   deg     = (int*)(h1 + ND);             // N_NODES
    int*   cursor  = deg + N_NODES;               // N_NODES (contiguous w/ deg for zeroing)
    int*   partial = cursor + N_NODES;            // N_NODES
    int*   rowptr  = partial + N_NODES;           // N_NODES+1
    int*   csums   = rowptr + N_NODES + 1;        // 256
    int*   coffs   = csums + 256;                 // 256
    int*   esrc    = coffs + 256;                 // N_EDGES_C
    // total ~ 5*12.8MB + 1.6MB + 6.4MB ~ 72MB

    const int B = 256;
    const int gEdge   = (N_EDGES_C + B - 1) / B;
    const int gNode32 = (N_NODES * 32 + B - 1) / B;
    const int gNode16 = (N_NODES * 16 + B - 1) / B;
    const int gNode   = (N_NODES + B - 1) / B;
    const int gZeroI  = (2 * N_NODES + B - 1) / B;
    // gather grids: waves_needed = ceil(N_NODES / G); threads = waves*64
    const int gGat32  = ((N_NODES + 1) / 2 * 64 + B - 1) / B + 1;
    const int gGat16  = ((N_NODES + 3) / 4 * 64 + B - 1) / B + 1;

    detect_kernel<<<1, 64, 0, stream>>>(emb, ei, flags);

    // ---- CSR build (shared by both layers) ----
    zero_i<<<gZeroI, B, 0, stream>>>(deg, 2 * N_NODES);
    hist_deg<<<gEdge, B, 0, stream>>>(ei, flags, deg);
    scan_chunk<<<N_CHUNKS, SCAN_CHUNK, 0, stream>>>(deg, partial, csums);
    scan_sums<<<1, 256, 0, stream>>>(csums, coffs);
    add_offs<<<gNode, B, 0, stream>>>(partial, coffs, rowptr);
    scatter_src<<<gEdge, B, 0, stream>>>(ei, flags, rowptr, cursor, esrc);

    // ---- Layer 1 (32 -> 32) ----
    node_linear<32, 32, false><<<gNode32, B, 0, stream>>>(
        emb, Wq1, bq1, Wk1, bk1, Wv1, bv1, Ws1, bs1, flags, q, k, v, s);
    gather_attn<32, false><<<gGat32, B, 0, stream>>>(
        rowptr, esrc, q, k, v, s, nullptr, nullptr, flags, h1, nullptr);

    // ---- Layer 2 (32 -> 16) + output linear ----
    node_linear<32, 16, true><<<gNode16, B, 0, stream>>>(
        h1, Wq2, bq2, Wk2, bk2, Wv2, bv2, Ws2, bs2, flags, q, k, v, s);
    gather_attn<16, true><<<gGat16, B, 0, stream>>>(
        rowptr, esrc, q, k, v, s, Wo, bo, flags, nullptr, d_out);
}

// Round 4
// 540.238 us; speedup vs baseline: 8.6352x; 1.3416x over previous
//
#include <hip/hip_runtime.h>
#include <hip/hip_bf16.h>

typedef __hip_bfloat16 bf16;

#define N_NODES 100000
#define N_EDGES_C 1600000
#define SCAN_CHUNK 512
#define N_CHUNKS ((N_NODES + SCAN_CHUNK - 1) / SCAN_CHUNK)   // 196

// ---------- runtime dtype helpers (flags[0]=floats-are-bf16, flags[1]=indices-are-int64) ----------
__device__ __forceinline__ float ldf(const void* p, long i, int isbf) {
    return isbf ? __bfloat162float(((const bf16*)p)[i]) : ((const float*)p)[i];
}
__device__ __forceinline__ int ldidx(const int* ei, long pos, int is64) {
    return is64 ? ei[2 * pos] : ei[pos];   // int64 LE: low word at 2*pos
}

// ---------- dtype detection ----------
__global__ void detect_kernel(const void* emb, const int* ei, int* flags) {
    if (blockIdx.x == 0 && threadIdx.x == 0) {
        const bf16* pb = (const bf16*)emb;
        int big = 0;
        for (int i = 0; i < 256; i++) {
            float v = __bfloat162float(pb[i]);
            if (!(v > -1.0e6f && v < 1.0e6f)) big++;  // f32-viewed-as-bf16 => ~42% huge/nan
        }
        flags[0] = (big <= 8) ? 1 : 0;
        int nz = 0;
        for (int i = 1; i < 256; i += 2) nz += (ei[i] != 0) ? 1 : 0;
        flags[1] = (nz == 0) ? 1 : 0;     // int64 => odd int32 words all zero
    }
}

// ---------- one-time casts to branch-free f32 ----------
__global__ void cast_emb(const void* __restrict__ X, const int* __restrict__ flags,
                         float* __restrict__ XF, int n) {
    int i = blockIdx.x * blockDim.x + threadIdx.x;
    if (i >= n) return;
    XF[i] = ldf(X, i, flags[0]);
}

__global__ void cast_params(
    const void* Wq1, const void* bq1, const void* Wk1, const void* bk1,
    const void* Wv1, const void* bv1, const void* Ws1, const void* bs1,
    const void* Wq2, const void* bq2, const void* Wk2, const void* bk2,
    const void* Wv2, const void* bv2, const void* Ws2, const void* bs2,
    const void* Wo, const void* bo, const int* __restrict__ flags,
    float* __restrict__ wp1, float* __restrict__ bp1,
    float* __restrict__ wp2, float* __restrict__ bp2, float* __restrict__ woF) {
    int isbf = flags[0];
    int t = threadIdx.x;
    for (int i = t; i < 1024; i += 256) {
        wp1[i]        = ldf(Wq1, i, isbf);
        wp1[1024 + i] = ldf(Wk1, i, isbf);
        wp1[2048 + i] = ldf(Wv1, i, isbf);
        wp1[3072 + i] = ldf(Ws1, i, isbf);
    }
    for (int i = t; i < 512; i += 256) {
        wp2[i]        = ldf(Wq2, i, isbf);
        wp2[512 + i]  = ldf(Wk2, i, isbf);
        wp2[1024 + i] = ldf(Wv2, i, isbf);
        wp2[1536 + i] = ldf(Ws2, i, isbf);
    }
    if (t < 32) {
        bp1[t] = ldf(bq1, t, isbf); bp1[32 + t] = ldf(bk1, t, isbf);
        bp1[64 + t] = ldf(bv1, t, isbf); bp1[96 + t] = ldf(bs1, t, isbf);
        woF[t] = ldf(Wo, t, isbf);
    }
    if (t < 16) {
        bp2[t] = ldf(bq2, t, isbf); bp2[16 + t] = ldf(bk2, t, isbf);
        bp2[32 + t] = ldf(bv2, t, isbf); bp2[48 + t] = ldf(bs2, t, isbf);
    }
    if (t < 2) woF[32 + t] = ldf(bo, t, isbf);
}

__global__ void zero_i(int* __restrict__ p, int n) {
    int i = blockIdx.x * blockDim.x + threadIdx.x;
    if (i < n) p[i] = 0;
}

// ---------- CSR build ----------
__global__ void hist_deg(const int* __restrict__ ei, const int* __restrict__ flags,
                         int* __restrict__ deg) {
    int e = blockIdx.x * blockDim.x + threadIdx.x;
    if (e >= N_EDGES_C) return;
    int d = ldidx(ei, (long)N_EDGES_C + e, flags[1]);
    atomicAdd(&deg[d], 1);
}

__global__ void scan_chunk(const int* __restrict__ deg, int* __restrict__ partial,
                           int* __restrict__ chunkSums) {
    __shared__ int tmp[SCAN_CHUNK];
    int i = blockIdx.x * SCAN_CHUNK + threadIdx.x;
    int v = (i < N_NODES) ? deg[i] : 0;
    tmp[threadIdx.x] = v;
    __syncthreads();
    for (int off = 1; off < SCAN_CHUNK; off <<= 1) {
        int t = (threadIdx.x >= off) ? tmp[threadIdx.x - off] : 0;
        __syncthreads();
        tmp[threadIdx.x] += t;
        __syncthreads();
    }
    if (i < N_NODES) partial[i] = tmp[threadIdx.x] - v;  // exclusive
    if (threadIdx.x == SCAN_CHUNK - 1) chunkSums[blockIdx.x] = tmp[threadIdx.x];
}

__global__ void scan_sums(int* __restrict__ chunkSums, int* __restrict__ chunkOffs) {
    __shared__ int tmp[256];
    int v = (threadIdx.x < N_CHUNKS) ? chunkSums[threadIdx.x] : 0;
    tmp[threadIdx.x] = v;
    __syncthreads();
    for (int off = 1; off < 256; off <<= 1) {
        int t = (threadIdx.x >= off) ? tmp[threadIdx.x - off] : 0;
        __syncthreads();
        tmp[threadIdx.x] += t;
        __syncthreads();
    }
    if (threadIdx.x < N_CHUNKS) chunkOffs[threadIdx.x] = tmp[threadIdx.x] - v;
}

__global__ void add_offs(const int* __restrict__ partial, const int* __restrict__ chunkOffs,
                         int* __restrict__ rowptr) {
    int i = blockIdx.x * blockDim.x + threadIdx.x;
    if (i < N_NODES) rowptr[i] = partial[i] + chunkOffs[i / SCAN_CHUNK];
    if (i == 0) rowptr[N_NODES] = N_EDGES_C;
}

__global__ void scatter_src(const int* __restrict__ ei, const int* __restrict__ flags,
                            const int* __restrict__ rowptr, int* __restrict__ cursor,
                            int* __restrict__ esrc) {
    int e = blockIdx.x * blockDim.x + threadIdx.x;
    if (e >= N_EDGES_C) return;
    const int is64 = flags[1];
    int s = ldidx(ei, e, is64);
    int d = ldidx(ei, (long)N_EDGES_C + e, is64);
    int pos = rowptr[d] + atomicAdd(&cursor[d], 1);
    esrc[pos] = s;
}

// ---------- node linears (branch-free f32, LDS-staged, float4 everywhere) ----------
// q,k,v,s = X @ W{q,k,v,s} + b.  thread = (node, col-quad); X tile + weights in LDS.
template <int DOUT>
__global__ void node_linear_f32(const float* __restrict__ X,      // [N,32] f32
                                const float* __restrict__ wpack,  // [4][32][DOUT] f32
                                const float* __restrict__ bpack,  // [4][DOUT] f32
                                float* __restrict__ q, float* __restrict__ k,
                                float* __restrict__ v, float* __restrict__ s) {
    const int TPN = DOUT / 4;     // threads per node (8 or 4)
    const int NPB = 256 / TPN;    // nodes per block (32 or 64)
    const int W_ELEMS = 4 * 32 * DOUT;
    __shared__ float sW[W_ELEMS];
    __shared__ float sb[4 * DOUT];
    __shared__ float sX[NPB * 36];  // pad stride 36 (16B-aligned, conflict-free)

    const float4* wp4 = (const float4*)wpack;
    float4* sW4 = (float4*)sW;
    for (int i = threadIdx.x; i < W_ELEMS / 4; i += 256) sW4[i] = wp4[i];
    if (threadIdx.x < 4 * DOUT) sb[threadIdx.x] = bpack[threadIdx.x];
    const int base = blockIdx.x * NPB * 32;
    for (int i = threadIdx.x; i < NPB * 32; i += 256) {
        int g = base + i;
        sX[(i >> 5) * 36 + (i & 31)] = (g < N_NODES * 32) ? X[g] : 0.0f;
    }
    __syncthreads();

    int l = threadIdx.x / TPN;
    int c4 = (threadIdx.x % TPN) * 4;
    int n = blockIdx.x * NPB + l;
    if (n >= N_NODES) return;

    float xr[32];
#pragma unroll
    for (int j = 0; j < 8; j++) {
        float4 t = *(const float4*)&sX[l * 36 + 4 * j];
        xr[4 * j] = t.x; xr[4 * j + 1] = t.y; xr[4 * j + 2] = t.z; xr[4 * j + 3] = t.w;
    }
    float acc[4][4];
#pragma unroll
    for (int m = 0; m < 4; m++)
#pragma unroll
        for (int j = 0; j < 4; j++) acc[m][j] = sb[m * DOUT + c4 + j];

#pragma unroll
    for (int t = 0; t < 32; t++) {
#pragma unroll
        for (int m = 0; m < 4; m++) {
            float4 w = *(const float4*)&sW[(m * 32 + t) * DOUT + c4];
            acc[m][0] += xr[t] * w.x;
            acc[m][1] += xr[t] * w.y;
            acc[m][2] += xr[t] * w.z;
            acc[m][3] += xr[t] * w.w;
        }
    }
    size_t o = (size_t)n * DOUT + c4;
    *(float4*)&q[o] = make_float4(acc[0][0], acc[0][1], acc[0][2], acc[0][3]);
    *(float4*)&k[o] = make_float4(acc[1][0], acc[1][1], acc[1][2], acc[1][3]);
    *(float4*)&v[o] = make_float4(acc[2][0], acc[2][1], acc[2][2], acc[2][3]);
    *(float4*)&s[o] = make_float4(acc[3][0], acc[3][1], acc[3][2], acc[3][3]);
}

// ---------- fused gather attention (one D-lane group per dst, online softmax) ----------
template <int D, bool LAYER2>
__global__ void gather_attn(const int* __restrict__ rowptr, const int* __restrict__ esrc,
                            const float* __restrict__ q, const float* __restrict__ k,
                            const float* __restrict__ v, const float* __restrict__ s,
                            const float* __restrict__ woF,  // [32]=Wo, [32..33]=bo (f32)
                            const int* __restrict__ flags,
                            float* __restrict__ h1, void* __restrict__ out) {
    const int G = 64 / D;  // dst groups per wave
    int lane = threadIdx.x & 63;
    int wave = (blockIdx.x * blockDim.x + threadIdx.x) >> 6;
    int g = lane / D;
    int c = lane % D;
    int dst = wave * G + g;
    if (dst >= N_NODES) return;  // uniform within a D-lane group

    const float rsq = (D == 32) ? 0.17677669529663689f : 0.25f;  // 1/sqrt(D)
    float qc = q[(size_t)dst * D + c];
    int beg = rowptr[dst], end = rowptr[dst + 1];

    float m = -3.0e38f, sum = 0.0f, acc = 0.0f;
    float kc_n = 0.0f, vc_n = 0.0f;
    if (beg < end) {
        int sn = esrc[beg];
        kc_n = k[(size_t)sn * D + c];
        vc_n = v[(size_t)sn * D + c];
    }
    for (int e = beg; e < end; e++) {
        float kc = kc_n, vc = vc_n;
        if (e + 1 < end) {                 // prefetch next edge's rows
            int sn = esrc[e + 1];
            kc_n = k[(size_t)sn * D + c];
            vc_n = v[(size_t)sn * D + c];
        }
        float p = qc * kc;
#pragma unroll
        for (int mask = D / 2; mask >= 1; mask >>= 1) p += __shfl_xor(p, mask, D);
        float al = p * rsq;
        float mn = fmaxf(m, al);
        float scale = __expf(m - mn);      // first iter: exp(-inf)=0
        float ex = __expf(al - mn);
        sum = sum * scale + ex;
        acc = acc * scale + vc * ex;
        m = mn;
    }
    float h = acc / (sum + 1e-16f) + s[(size_t)dst * D + c];
    h = h > 0.0f ? h : 0.0f;

    if (!LAYER2) {
        h1[(size_t)dst * D + c] = h;
    } else {
        float p0 = h * woF[c * 2 + 0];
        float p1 = h * woF[c * 2 + 1];
#pragma unroll
        for (int mask = D / 2; mask >= 1; mask >>= 1) {
            p0 += __shfl_xor(p0, mask, D);
            p1 += __shfl_xor(p1, mask, D);
        }
        if (c == 0) {
            float o0 = p0 + woF[32];
            float o1 = p1 + woF[33];
            if (flags[0]) {
                ((bf16*)out)[dst * 2 + 0] = __float2bfloat16(o0);
                ((bf16*)out)[dst * 2 + 1] = __float2bfloat16(o1);
            } else {
                ((float*)out)[dst * 2 + 0] = o0;
                ((float*)out)[dst * 2 + 1] = o1;
            }
        }
    }
}

extern "C" void kernel_launch(void* const* d_in, const int* in_sizes, int n_in,
                              void* d_out, int out_size, void* d_ws, size_t ws_size,
                              hipStream_t stream) {
    const int* ei  = (const int*)d_in[0];
    const void* emb = d_in[1];
    const void *Wq1 = d_in[2],  *bq1 = d_in[3];
    const void *Wk1 = d_in[4],  *bk1 = d_in[5];
    const void *Wv1 = d_in[6],  *bv1 = d_in[7];
    const void *Ws1 = d_in[8],  *bs1 = d_in[9];
    const void *Wq2 = d_in[10], *bq2 = d_in[11];
    const void *Wk2 = d_in[12], *bk2 = d_in[13];
    const void *Wv2 = d_in[14], *bv2 = d_in[15];
    const void *Ws2 = d_in[16], *bs2 = d_in[17];
    const void *Wo  = d_in[18], *bo  = d_in[19];

    // Workspace layout (floats). embF aliases h1: embF dead after node_linear L1,
    // h1 first written by gather_attn L1 (which runs after).
    const size_t ND = (size_t)N_NODES * 32;
    int*   flags  = (int*)d_ws;                   // 64
    float* wp1    = (float*)d_ws + 64;            // 4096
    float* bp1    = wp1 + 4096;                   // 128
    float* wp2    = bp1 + 128;                    // 2048
    float* bp2    = wp2 + 2048;                   // 64
    float* woF    = bp2 + 64;                     // 64
    float* q      = woF + 64;                     // ND
    float* k      = q + ND;                       // ND
    float* v      = k + ND;                       // ND
    float* s      = v + ND;                       // ND
    float* embF   = s + ND;                       // ND (aliased with h1)
    float* h1     = embF;
    int*   deg     = (int*)(embF + ND);           // N_NODES
    int*   cursor  = deg + N_NODES;               // N_NODES
    int*   partial = cursor + N_NODES;            // N_NODES
    int*   rowptr  = partial + N_NODES;           // N_NODES+1
    int*   csums   = rowptr + N_NODES + 1;        // 256
    int*   coffs   = csums + 256;                 // 256
    int*   esrc    = coffs + 256;                 // N_EDGES_C
    // total ~ 64 MB + 8 MB = 72 MB

    const int B = 256;
    const int gEdge   = (N_EDGES_C + B - 1) / B;
    const int gNode   = (N_NODES + B - 1) / B;
    const int gZeroI  = (2 * N_NODES + B - 1) / B;
    const int gCast   = (N_NODES * 32 + B - 1) / B;
    const int gNL32   = (N_NODES + 31) / 32;      // NPB=32
    const int gNL16   = (N_NODES + 63) / 64;      // NPB=64
    const int gGat32  = ((N_NODES + 1) / 2 * 64 + B - 1) / B + 1;
    const int gGat16  = ((N_NODES + 3) / 4 * 64 + B - 1) / B + 1;

    detect_kernel<<<1, 64, 0, stream>>>(emb, ei, flags);
    cast_emb<<<gCast, B, 0, stream>>>(emb, flags, embF, N_NODES * 32);
    cast_params<<<1, B, 0, stream>>>(Wq1, bq1, Wk1, bk1, Wv1, bv1, Ws1, bs1,
                                     Wq2, bq2, Wk2, bk2, Wv2, bv2, Ws2, bs2,
                                     Wo, bo, flags, wp1, bp1, wp2, bp2, woF);

    // ---- CSR build (shared by both layers) ----
    zero_i<<<gZeroI, B, 0, stream>>>(deg, 2 * N_NODES);
    hist_deg<<<gEdge, B, 0, stream>>>(ei, flags, deg);
    scan_chunk<<<N_CHUNKS, SCAN_CHUNK, 0, stream>>>(deg, partial, csums);
    scan_sums<<<1, 256, 0, stream>>>(csums, coffs);
    add_offs<<<gNode, B, 0, stream>>>(partial, coffs, rowptr);
    scatter_src<<<gEdge, B, 0, stream>>>(ei, flags, rowptr, cursor, esrc);

    // ---- Layer 1 (32 -> 32) ----
    node_linear_f32<32><<<gNL32, B, 0, stream>>>(embF, wp1, bp1, q, k, v, s);
    gather_attn<32, false><<<gGat32, B, 0, stream>>>(
        rowptr, esrc, q, k, v, s, woF, flags, h1, nullptr);

    // ---- Layer 2 (32 -> 16) + output linear ----
    node_linear_f32<16><<<gNL16, B, 0, stream>>>(h1, wp2, bp2, q, k, v, s);
    gather_attn<16, true><<<gGat16, B, 0, stream>>>(
        rowptr, esrc, q, k, v, s, woF, flags, nullptr, d_out);
}

// Round 5
// 521.826 us; speedup vs baseline: 8.9399x; 1.0353x over previous
//
#include <hip/hip_runtime.h>
#include <hip/hip_bf16.h>

typedef __hip_bfloat16 bf16;

#define N_NODES 100000
#define N_EDGES_C 1600000
#define SCAN_CHUNK 512
#define N_CHUNKS ((N_NODES + SCAN_CHUNK - 1) / SCAN_CHUNK)   // 196

// ---------- runtime dtype helpers (flags[0]=floats-are-bf16, flags[1]=indices-are-int64) ----------
__device__ __forceinline__ float ldf(const void* p, long i, int isbf) {
    return isbf ? __bfloat162float(((const bf16*)p)[i]) : ((const float*)p)[i];
}
__device__ __forceinline__ int ldidx(const int* ei, long pos, int is64) {
    return is64 ? ei[2 * pos] : ei[pos];   // int64 LE: low word at 2*pos
}

// ---------- dtype detection ----------
__global__ void detect_kernel(const void* emb, const int* ei, int* flags) {
    if (blockIdx.x == 0 && threadIdx.x == 0) {
        const bf16* pb = (const bf16*)emb;
        int big = 0;
        for (int i = 0; i < 256; i++) {
            float v = __bfloat162float(pb[i]);
            if (!(v > -1.0e6f && v < 1.0e6f)) big++;  // f32-viewed-as-bf16 => ~42% huge/nan
        }
        flags[0] = (big <= 8) ? 1 : 0;
        int nz = 0;
        for (int i = 1; i < 256; i += 2) nz += (ei[i] != 0) ? 1 : 0;
        flags[1] = (nz == 0) ? 1 : 0;     // int64 => odd int32 words all zero
    }
}

// ---------- one-time casts to branch-free f32 ----------
__global__ void cast_emb(const void* __restrict__ X, const int* __restrict__ flags,
                         float* __restrict__ XF, int n) {
    int i = blockIdx.x * blockDim.x + threadIdx.x;
    if (i >= n) return;
    XF[i] = ldf(X, i, flags[0]);
}

__global__ void cast_params(
    const void* Wq1, const void* bq1, const void* Wk1, const void* bk1,
    const void* Wv1, const void* bv1, const void* Ws1, const void* bs1,
    const void* Wq2, const void* bq2, const void* Wk2, const void* bk2,
    const void* Wv2, const void* bv2, const void* Ws2, const void* bs2,
    const void* Wo, const void* bo, const int* __restrict__ flags,
    float* __restrict__ wp1, float* __restrict__ bp1,
    float* __restrict__ wp2, float* __restrict__ bp2, float* __restrict__ woF) {
    int isbf = flags[0];
    int t = threadIdx.x;
    for (int i = t; i < 1024; i += 256) {
        wp1[i]        = ldf(Wq1, i, isbf);
        wp1[1024 + i] = ldf(Wk1, i, isbf);
        wp1[2048 + i] = ldf(Wv1, i, isbf);
        wp1[3072 + i] = ldf(Ws1, i, isbf);
    }
    for (int i = t; i < 512; i += 256) {
        wp2[i]        = ldf(Wq2, i, isbf);
        wp2[512 + i]  = ldf(Wk2, i, isbf);
        wp2[1024 + i] = ldf(Wv2, i, isbf);
        wp2[1536 + i] = ldf(Ws2, i, isbf);
    }
    if (t < 32) {
        bp1[t] = ldf(bq1, t, isbf); bp1[32 + t] = ldf(bk1, t, isbf);
        bp1[64 + t] = ldf(bv1, t, isbf); bp1[96 + t] = ldf(bs1, t, isbf);
        woF[t] = ldf(Wo, t, isbf);
    }
    if (t < 16) {
        bp2[t] = ldf(bq2, t, isbf); bp2[16 + t] = ldf(bk2, t, isbf);
        bp2[32 + t] = ldf(bv2, t, isbf); bp2[48 + t] = ldf(bs2, t, isbf);
    }
    if (t < 2) woF[32 + t] = ldf(bo, t, isbf);
}

__global__ void zero_i(int* __restrict__ p, int n) {
    int i = blockIdx.x * blockDim.x + threadIdx.x;
    if (i < n) p[i] = 0;
}

// ---------- CSR build ----------
__global__ void hist_deg(const int* __restrict__ ei, const int* __restrict__ flags,
                         int* __restrict__ deg) {
    int e = blockIdx.x * blockDim.x + threadIdx.x;
    if (e >= N_EDGES_C) return;
    int d = ldidx(ei, (long)N_EDGES_C + e, flags[1]);
    atomicAdd(&deg[d], 1);
}

__global__ void scan_chunk(const int* __restrict__ deg, int* __restrict__ partial,
                           int* __restrict__ chunkSums) {
    __shared__ int tmp[SCAN_CHUNK];
    int i = blockIdx.x * SCAN_CHUNK + threadIdx.x;
    int v = (i < N_NODES) ? deg[i] : 0;
    tmp[threadIdx.x] = v;
    __syncthreads();
    for (int off = 1; off < SCAN_CHUNK; off <<= 1) {
        int t = (threadIdx.x >= off) ? tmp[threadIdx.x - off] : 0;
        __syncthreads();
        tmp[threadIdx.x] += t;
        __syncthreads();
    }
    if (i < N_NODES) partial[i] = tmp[threadIdx.x] - v;  // exclusive
    if (threadIdx.x == SCAN_CHUNK - 1) chunkSums[blockIdx.x] = tmp[threadIdx.x];
}

__global__ void scan_sums(int* __restrict__ chunkSums, int* __restrict__ chunkOffs) {
    __shared__ int tmp[256];
    int v = (threadIdx.x < N_CHUNKS) ? chunkSums[threadIdx.x] : 0;
    tmp[threadIdx.x] = v;
    __syncthreads();
    for (int off = 1; off < 256; off <<= 1) {
        int t = (threadIdx.x >= off) ? tmp[threadIdx.x - off] : 0;
        __syncthreads();
        tmp[threadIdx.x] += t;
        __syncthreads();
    }
    if (threadIdx.x < N_CHUNKS) chunkOffs[threadIdx.x] = tmp[threadIdx.x] - v;
}

// Writes rowptr AND pre-initializes cursor=rowptr (shortens scatter's dep chain).
__global__ void add_offs(const int* __restrict__ partial, const int* __restrict__ chunkOffs,
                         int* __restrict__ rowptr, int* __restrict__ cursor) {
    int i = blockIdx.x * blockDim.x + threadIdx.x;
    if (i < N_NODES) {
        int r = partial[i] + chunkOffs[i / SCAN_CHUNK];
        rowptr[i] = r;
        cursor[i] = r;
    }
    if (i == 0) rowptr[N_NODES] = N_EDGES_C;
}

__global__ void scatter_src(const int* __restrict__ ei, const int* __restrict__ flags,
                            int* __restrict__ cursor, int* __restrict__ esrc) {
    int e = blockIdx.x * blockDim.x + threadIdx.x;
    if (e >= N_EDGES_C) return;
    const int is64 = flags[1];
    int s = ldidx(ei, e, is64);
    int d = ldidx(ei, (long)N_EDGES_C + e, is64);
    int pos = atomicAdd(&cursor[d], 1);   // cursor pre-init'd to rowptr
    esrc[pos] = s;
}

// ---------- node linears (branch-free f32, LDS-staged, float4 everywhere) ----------
// q = X@Wq+bq; kv packed [n][2*DOUT] = [k(n) | v(n)]; s = X@Ws+bs.
template <int DOUT>
__global__ void node_linear_f32(const float* __restrict__ X,      // [N,32] f32
                                const float* __restrict__ wpack,  // [4][32][DOUT] f32
                                const float* __restrict__ bpack,  // [4][DOUT] f32
                                float* __restrict__ q, float* __restrict__ kv,
                                float* __restrict__ s) {
    const int TPN = DOUT / 4;     // threads per node (8 or 4)
    const int NPB = 256 / TPN;    // nodes per block (32 or 64)
    const int W_ELEMS = 4 * 32 * DOUT;
    __shared__ float sW[W_ELEMS];
    __shared__ float sb[4 * DOUT];
    __shared__ float sX[NPB * 36];  // pad stride 36 (16B-aligned, conflict-free)

    const float4* wp4 = (const float4*)wpack;
    float4* sW4 = (float4*)sW;
    for (int i = threadIdx.x; i < W_ELEMS / 4; i += 256) sW4[i] = wp4[i];
    if (threadIdx.x < 4 * DOUT) sb[threadIdx.x] = bpack[threadIdx.x];
    const int base = blockIdx.x * NPB * 32;
    for (int i = threadIdx.x; i < NPB * 32; i += 256) {
        int g = base + i;
        sX[(i >> 5) * 36 + (i & 31)] = (g < N_NODES * 32) ? X[g] : 0.0f;
    }
    __syncthreads();

    int l = threadIdx.x / TPN;
    int c4 = (threadIdx.x % TPN) * 4;
    int n = blockIdx.x * NPB + l;
    if (n >= N_NODES) return;

    float xr[32];
#pragma unroll
    for (int j = 0; j < 8; j++) {
        float4 t = *(const float4*)&sX[l * 36 + 4 * j];
        xr[4 * j] = t.x; xr[4 * j + 1] = t.y; xr[4 * j + 2] = t.z; xr[4 * j + 3] = t.w;
    }
    float acc[4][4];
#pragma unroll
    for (int m = 0; m < 4; m++)
#pragma unroll
        for (int j = 0; j < 4; j++) acc[m][j] = sb[m * DOUT + c4 + j];

#pragma unroll
    for (int t = 0; t < 32; t++) {
#pragma unroll
        for (int m = 0; m < 4; m++) {
            float4 w = *(const float4*)&sW[(m * 32 + t) * DOUT + c4];
            acc[m][0] += xr[t] * w.x;
            acc[m][1] += xr[t] * w.y;
            acc[m][2] += xr[t] * w.z;
            acc[m][3] += xr[t] * w.w;
        }
    }
    size_t o = (size_t)n * DOUT + c4;
    size_t okv = (size_t)n * 2 * DOUT + c4;
    *(float4*)&q[o]          = make_float4(acc[0][0], acc[0][1], acc[0][2], acc[0][3]);
    *(float4*)&kv[okv]       = make_float4(acc[1][0], acc[1][1], acc[1][2], acc[1][3]);
    *(float4*)&kv[okv + DOUT]= make_float4(acc[2][0], acc[2][1], acc[2][2], acc[2][3]);
    *(float4*)&s[o]          = make_float4(acc[3][0], acc[3][1], acc[3][2], acc[3][3]);
}

// ---------- fused gather attention ----------
// No max-subtraction (ratio-identical; alpha clamped +-80): every edge iteration
// is independent -> unroll x2, dual accumulators, 2-deep prefetch.
template <int D>
__device__ __forceinline__ float grpsum(float p) {
#pragma unroll
    for (int m = D / 2; m >= 1; m >>= 1) p += __shfl_xor(p, m, D);
    return p;
}

template <int D, bool LAYER2>
__global__ void gather_attn(const int* __restrict__ rowptr, const int* __restrict__ esrc,
                            const float* __restrict__ q, const float* __restrict__ kv,
                            const float* __restrict__ s,
                            const float* __restrict__ woF,  // [32]=Wo, [32..33]=bo (f32)
                            const int* __restrict__ flags,
                            float* __restrict__ h1, void* __restrict__ out) {
    const int G = 64 / D;  // dst groups per wave
    int lane = threadIdx.x & 63;
    int wave = (blockIdx.x * blockDim.x + threadIdx.x) >> 6;
    int g = lane / D;
    int c = lane % D;
    int dst = wave * G + g;
    if (dst >= N_NODES) return;  // uniform within a D-lane group

    const float rsq = (D == 32) ? 0.17677669529663689f : 0.25f;  // 1/sqrt(D)
    float qc = q[(size_t)dst * D + c];
    int beg = rowptr[dst], end = rowptr[dst + 1];

    float sum0 = 0.0f, sum1 = 0.0f, acc0 = 0.0f, acc1 = 0.0f;

    // 2-deep software pipeline
    int sn0 = (beg < end) ? esrc[beg] : 0;
    int sn1 = (beg + 1 < end) ? esrc[beg + 1] : 0;
    float ka = kv[(size_t)sn0 * 2 * D + c],     va = kv[(size_t)sn0 * 2 * D + D + c];
    float kb = kv[(size_t)sn1 * 2 * D + c],     vb = kv[(size_t)sn1 * 2 * D + D + c];

    for (int e = beg; e < end; e += 2) {
        float kA = ka, vA = va, kB = kb, vB = vb;
        if (e + 2 < end) {
            int sn = esrc[e + 2];
            ka = kv[(size_t)sn * 2 * D + c]; va = kv[(size_t)sn * 2 * D + D + c];
        }
        if (e + 3 < end) {
            int sn = esrc[e + 3];
            kb = kv[(size_t)sn * 2 * D + c]; vb = kv[(size_t)sn * 2 * D + D + c];
        }
        float p0 = grpsum<D>(qc * kA);
        float ex0 = __expf(fminf(fmaxf(p0 * rsq, -80.0f), 80.0f));
        sum0 += ex0; acc0 += vA * ex0;
        if (e + 1 < end) {
            float p1 = grpsum<D>(qc * kB);
            float ex1 = __expf(fminf(fmaxf(p1 * rsq, -80.0f), 80.0f));
            sum1 += ex1; acc1 += vB * ex1;
        }
    }
    float sum = sum0 + sum1, acc = acc0 + acc1;
    float h = acc / (sum + 1e-16f) + s[(size_t)dst * D + c];
    h = h > 0.0f ? h : 0.0f;

    if (!LAYER2) {
        h1[(size_t)dst * D + c] = h;
    } else {
        float p0 = h * woF[c * 2 + 0];
        float p1 = h * woF[c * 2 + 1];
        p0 = grpsum<D>(p0);
        p1 = grpsum<D>(p1);
        if (c == 0) {
            float o0 = p0 + woF[32];
            float o1 = p1 + woF[33];
            if (flags[0]) {
                ((bf16*)out)[dst * 2 + 0] = __float2bfloat16(o0);
                ((bf16*)out)[dst * 2 + 1] = __float2bfloat16(o1);
            } else {
                ((float*)out)[dst * 2 + 0] = o0;
                ((float*)out)[dst * 2 + 1] = o1;
            }
        }
    }
}

extern "C" void kernel_launch(void* const* d_in, const int* in_sizes, int n_in,
                              void* d_out, int out_size, void* d_ws, size_t ws_size,
                              hipStream_t stream) {
    const int* ei  = (const int*)d_in[0];
    const void* emb = d_in[1];
    const void *Wq1 = d_in[2],  *bq1 = d_in[3];
    const void *Wk1 = d_in[4],  *bk1 = d_in[5];
    const void *Wv1 = d_in[6],  *bv1 = d_in[7];
    const void *Ws1 = d_in[8],  *bs1 = d_in[9];
    const void *Wq2 = d_in[10], *bq2 = d_in[11];
    const void *Wk2 = d_in[12], *bk2 = d_in[13];
    const void *Wv2 = d_in[14], *bv2 = d_in[15];
    const void *Ws2 = d_in[16], *bs2 = d_in[17];
    const void *Wo  = d_in[18], *bo  = d_in[19];

    // Workspace layout (floats). embF aliases h1 (embF dead after node_linear L1).
    const size_t ND = (size_t)N_NODES * 32;
    int*   flags  = (int*)d_ws;                   // 64
    float* wp1    = (float*)d_ws + 64;            // 4096
    float* bp1    = wp1 + 4096;                   // 128
    float* wp2    = bp1 + 128;                    // 2048
    float* bp2    = wp2 + 2048;                   // 64
    float* woF    = bp2 + 64;                     // 64
    float* q      = woF + 64;                     // ND
    float* s      = q + ND;                       // ND
    float* kvp    = s + ND;                       // 2*ND (layer1: [N][64]; layer2: [N][32])
    float* embF   = kvp + 2 * ND;                 // ND (aliased with h1)
    float* h1     = embF;
    int*   deg     = (int*)(embF + ND);           // N_NODES
    int*   cursor  = deg + N_NODES;               // N_NODES
    int*   partial = cursor + N_NODES;            // N_NODES
    int*   rowptr  = partial + N_NODES;           // N_NODES+1
    int*   csums   = rowptr + N_NODES + 1;        // 256
    int*   coffs   = csums + 256;                 // 256
    int*   esrc    = coffs + 256;                 // N_EDGES_C
    // total ~ 5*12.8MB + 8.2MB ~ 72MB (same as round 4)

    const int B = 256;
    const int gEdge   = (N_EDGES_C + B - 1) / B;
    const int gNode   = (N_NODES + B - 1) / B;
    const int gZeroI  = (N_NODES + B - 1) / B;
    const int gCast   = (N_NODES * 32 + B - 1) / B;
    const int gNL32   = (N_NODES + 31) / 32;      // NPB=32
    const int gNL16   = (N_NODES + 63) / 64;      // NPB=64
    const int gGat32  = ((N_NODES + 1) / 2 * 64 + B - 1) / B;
    const int gGat16  = ((N_NODES + 3) / 4 * 64 + B - 1) / B;

    detect_kernel<<<1, 64, 0, stream>>>(emb, ei, flags);
    cast_emb<<<gCast, B, 0, stream>>>(emb, flags, embF, N_NODES * 32);
    cast_params<<<1, B, 0, stream>>>(Wq1, bq1, Wk1, bk1, Wv1, bv1, Ws1, bs1,
                                     Wq2, bq2, Wk2, bk2, Wv2, bv2, Ws2, bs2,
                                     Wo, bo, flags, wp1, bp1, wp2, bp2, woF);

    // ---- CSR build (shared by both layers) ----
    zero_i<<<gZeroI, B, 0, stream>>>(deg, N_NODES);
    hist_deg<<<gEdge, B, 0, stream>>>(ei, flags, deg);
    scan_chunk<<<N_CHUNKS, SCAN_CHUNK, 0, stream>>>(deg, partial, csums);
    scan_sums<<<1, 256, 0, stream>>>(csums, coffs);
    add_offs<<<gNode, B, 0, stream>>>(partial, coffs, rowptr, cursor);
    scatter_src<<<gEdge, B, 0, stream>>>(ei, flags, cursor, esrc);

    // ---- Layer 1 (32 -> 32) ----
    node_linear_f32<32><<<gNL32, B, 0, stream>>>(embF, wp1, bp1, q, kvp, s);
    gather_attn<32, false><<<gGat32, B, 0, stream>>>(
        rowptr, esrc, q, kvp, s, woF, flags, h1, nullptr);

    // ---- Layer 2 (32 -> 16) + output linear ----
    node_linear_f32<16><<<gNL16, B, 0, stream>>>(h1, wp2, bp2, q, kvp, s);
    gather_attn<16, true><<<gGat16, B, 0, stream>>>(
        rowptr, esrc, q, kvp, s, woF, flags, nullptr, d_out);
}

// Round 6
// 467.229 us; speedup vs baseline: 9.9846x; 1.1169x over previous
//
#include <hip/hip_runtime.h>
#include <hip/hip_bf16.h>

typedef __hip_bfloat16 bf16;

#define N_NODES 100000
#define N_EDGES_C 1600000
#define SCAN_CHUNK 512
#define N_CHUNKS ((N_NODES + SCAN_CHUNK - 1) / SCAN_CHUNK)   // 196
#define NSLICE 8                      // XCD count; heuristic blockIdx%8 -> XCD
#define NPS (N_NODES / NSLICE)        // 12500 dsts per slice (exact)

// ---------- runtime dtype helpers (flags[0]=floats-are-bf16, flags[1]=indices-are-int64) ----------
__device__ __forceinline__ float ldf(const void* p, long i, int isbf) {
    return isbf ? __bfloat162float(((const bf16*)p)[i]) : ((const float*)p)[i];
}
__device__ __forceinline__ int ldidx(const int* ei, long pos, int is64) {
    return is64 ? ei[2 * pos] : ei[pos];   // int64 LE: low word at 2*pos
}

// ---------- dtype detection ----------
__global__ void detect_kernel(const void* emb, const int* ei, int* flags) {
    if (blockIdx.x == 0 && threadIdx.x == 0) {
        const bf16* pb = (const bf16*)emb;
        int big = 0;
        for (int i = 0; i < 256; i++) {
            float v = __bfloat162float(pb[i]);
            if (!(v > -1.0e6f && v < 1.0e6f)) big++;  // f32-viewed-as-bf16 => ~42% huge/nan
        }
        flags[0] = (big <= 8) ? 1 : 0;
        int nz = 0;
        for (int i = 1; i < 256; i += 2) nz += (ei[i] != 0) ? 1 : 0;
        flags[1] = (nz == 0) ? 1 : 0;     // int64 => odd int32 words all zero
    }
}

// ---------- one-time casts to branch-free f32 ----------
__global__ void cast_emb(const void* __restrict__ X, const int* __restrict__ flags,
                         float* __restrict__ XF, int n) {
    int i = blockIdx.x * blockDim.x + threadIdx.x;
    if (i >= n) return;
    XF[i] = ldf(X, i, flags[0]);
}

__global__ void cast_params(
    const void* Wq1, const void* bq1, const void* Wk1, const void* bk1,
    const void* Wv1, const void* bv1, const void* Ws1, const void* bs1,
    const void* Wq2, const void* bq2, const void* Wk2, const void* bk2,
    const void* Wv2, const void* bv2, const void* Ws2, const void* bs2,
    const void* Wo, const void* bo, const int* __restrict__ flags,
    float* __restrict__ wp1, float* __restrict__ bp1,
    float* __restrict__ wp2, float* __restrict__ bp2, float* __restrict__ woF) {
    int isbf = flags[0];
    int t = threadIdx.x;
    for (int i = t; i < 1024; i += 256) {
        wp1[i]        = ldf(Wq1, i, isbf);
        wp1[1024 + i] = ldf(Wk1, i, isbf);
        wp1[2048 + i] = ldf(Wv1, i, isbf);
        wp1[3072 + i] = ldf(Ws1, i, isbf);
    }
    for (int i = t; i < 512; i += 256) {
        wp2[i]        = ldf(Wq2, i, isbf);
        wp2[512 + i]  = ldf(Wk2, i, isbf);
        wp2[1024 + i] = ldf(Wv2, i, isbf);
        wp2[1536 + i] = ldf(Ws2, i, isbf);
    }
    if (t < 32) {
        bp1[t] = ldf(bq1, t, isbf); bp1[32 + t] = ldf(bk1, t, isbf);
        bp1[64 + t] = ldf(bv1, t, isbf); bp1[96 + t] = ldf(bs1, t, isbf);
        woF[t] = ldf(Wo, t, isbf);
    }
    if (t < 16) {
        bp2[t] = ldf(bq2, t, isbf); bp2[16 + t] = ldf(bk2, t, isbf);
        bp2[32 + t] = ldf(bv2, t, isbf); bp2[48 + t] = ldf(bs2, t, isbf);
    }
    if (t < 2) woF[32 + t] = ldf(bo, t, isbf);
}

__global__ void zero_i(int* __restrict__ p, int n) {
    int i = blockIdx.x * blockDim.x + threadIdx.x;
    if (i < n) p[i] = 0;
}

// ---------- CSR build (XCD-sliced: block b handles dst range of slice b%NSLICE) ----------
// All atomics/stores for a dst-slice come from blocks with the same blockIdx%8, which
// the hardware (heuristically) places on one XCD -> lines stay in that XCD's L2 instead
// of ping-ponging across XCDs. Edge list re-reads are LLC-resident (12.8 MB << 256 MB).
__global__ void hist_deg_sliced(const int* __restrict__ ei, const int* __restrict__ flags,
                                int* __restrict__ deg) {
    const int is64 = flags[1];
    int slice = blockIdx.x % NSLICE;
    int chunk = blockIdx.x / NSLICE;
    int nchunks = gridDim.x / NSLICE;
    int lo = slice * NPS, hi = lo + NPS;
    for (int e = chunk * blockDim.x + threadIdx.x; e < N_EDGES_C; e += nchunks * blockDim.x) {
        int d = ldidx(ei, (long)N_EDGES_C + e, is64);
        if (d >= lo && d < hi) atomicAdd(&deg[d], 1);
    }
}

__global__ void scatter_src_sliced(const int* __restrict__ ei, const int* __restrict__ flags,
                                   int* __restrict__ cursor, int* __restrict__ esrc) {
    const int is64 = flags[1];
    int slice = blockIdx.x % NSLICE;
    int chunk = blockIdx.x / NSLICE;
    int nchunks = gridDim.x / NSLICE;
    int lo = slice * NPS, hi = lo + NPS;
    for (int e = chunk * blockDim.x + threadIdx.x; e < N_EDGES_C; e += nchunks * blockDim.x) {
        int d = ldidx(ei, (long)N_EDGES_C + e, is64);
        if (d >= lo && d < hi) {
            int s = ldidx(ei, e, is64);
            int pos = atomicAdd(&cursor[d], 1);   // cursor pre-init'd to rowptr
            esrc[pos] = s;
        }
    }
}

__global__ void scan_chunk(const int* __restrict__ deg, int* __restrict__ partial,
                           int* __restrict__ chunkSums) {
    __shared__ int tmp[SCAN_CHUNK];
    int i = blockIdx.x * SCAN_CHUNK + threadIdx.x;
    int v = (i < N_NODES) ? deg[i] : 0;
    tmp[threadIdx.x] = v;
    __syncthreads();
    for (int off = 1; off < SCAN_CHUNK; off <<= 1) {
        int t = (threadIdx.x >= off) ? tmp[threadIdx.x - off] : 0;
        __syncthreads();
        tmp[threadIdx.x] += t;
        __syncthreads();
    }
    if (i < N_NODES) partial[i] = tmp[threadIdx.x] - v;  // exclusive
    if (threadIdx.x == SCAN_CHUNK - 1) chunkSums[blockIdx.x] = tmp[threadIdx.x];
}

__global__ void scan_sums(int* __restrict__ chunkSums, int* __restrict__ chunkOffs) {
    __shared__ int tmp[256];
    int v = (threadIdx.x < N_CHUNKS) ? chunkSums[threadIdx.x] : 0;
    tmp[threadIdx.x] = v;
    __syncthreads();
    for (int off = 1; off < 256; off <<= 1) {
        int t = (threadIdx.x >= off) ? tmp[threadIdx.x - off] : 0;
        __syncthreads();
        tmp[threadIdx.x] += t;
        __syncthreads();
    }
    if (threadIdx.x < N_CHUNKS) chunkOffs[threadIdx.x] = tmp[threadIdx.x] - v;
}

// Writes rowptr AND pre-initializes cursor=rowptr.
__global__ void add_offs(const int* __restrict__ partial, const int* __restrict__ chunkOffs,
                         int* __restrict__ rowptr, int* __restrict__ cursor) {
    int i = blockIdx.x * blockDim.x + threadIdx.x;
    if (i < N_NODES) {
        int r = partial[i] + chunkOffs[i / SCAN_CHUNK];
        rowptr[i] = r;
        cursor[i] = r;
    }
    if (i == 0) rowptr[N_NODES] = N_EDGES_C;
}

// ---------- node linears (branch-free f32, LDS-staged, float4 everywhere) ----------
template <int DOUT>
__global__ void node_linear_f32(const float* __restrict__ X,      // [N,32] f32
                                const float* __restrict__ wpack,  // [4][32][DOUT] f32
                                const float* __restrict__ bpack,  // [4][DOUT] f32
                                float* __restrict__ q, float* __restrict__ kv,
                                float* __restrict__ s) {
    const int TPN = DOUT / 4;     // threads per node (8 or 4)
    const int NPB = 256 / TPN;    // nodes per block (32 or 64)
    const int W_ELEMS = 4 * 32 * DOUT;
    __shared__ float sW[W_ELEMS];
    __shared__ float sb[4 * DOUT];
    __shared__ float sX[NPB * 36];  // pad stride 36 (16B-aligned, conflict-free)

    const float4* wp4 = (const float4*)wpack;
    float4* sW4 = (float4*)sW;
    for (int i = threadIdx.x; i < W_ELEMS / 4; i += 256) sW4[i] = wp4[i];
    if (threadIdx.x < 4 * DOUT) sb[threadIdx.x] = bpack[threadIdx.x];
    const int base = blockIdx.x * NPB * 32;
    for (int i = threadIdx.x; i < NPB * 32; i += 256) {
        int g = base + i;
        sX[(i >> 5) * 36 + (i & 31)] = (g < N_NODES * 32) ? X[g] : 0.0f;
    }
    __syncthreads();

    int l = threadIdx.x / TPN;
    int c4 = (threadIdx.x % TPN) * 4;
    int n = blockIdx.x * NPB + l;
    if (n >= N_NODES) return;

    float xr[32];
#pragma unroll
    for (int j = 0; j < 8; j++) {
        float4 t = *(const float4*)&sX[l * 36 + 4 * j];
        xr[4 * j] = t.x; xr[4 * j + 1] = t.y; xr[4 * j + 2] = t.z; xr[4 * j + 3] = t.w;
    }
    float acc[4][4];
#pragma unroll
    for (int m = 0; m < 4; m++)
#pragma unroll
        for (int j = 0; j < 4; j++) acc[m][j] = sb[m * DOUT + c4 + j];

#pragma unroll
    for (int t = 0; t < 32; t++) {
#pragma unroll
        for (int m = 0; m < 4; m++) {
            float4 w = *(const float4*)&sW[(m * 32 + t) * DOUT + c4];
            acc[m][0] += xr[t] * w.x;
            acc[m][1] += xr[t] * w.y;
            acc[m][2] += xr[t] * w.z;
            acc[m][3] += xr[t] * w.w;
        }
    }
    size_t o = (size_t)n * DOUT + c4;
    size_t okv = (size_t)n * 2 * DOUT + c4;
    *(float4*)&q[o]          = make_float4(acc[0][0], acc[0][1], acc[0][2], acc[0][3]);
    *(float4*)&kv[okv]       = make_float4(acc[1][0], acc[1][1], acc[1][2], acc[1][3]);
    *(float4*)&kv[okv + DOUT]= make_float4(acc[2][0], acc[2][1], acc[2][2], acc[2][3]);
    *(float4*)&s[o]          = make_float4(acc[3][0], acc[3][1], acc[3][2], acc[3][3]);
}

// ---------- fused gather attention ----------
// No max-subtraction (ratio-identical; alpha clamped +-80): independent edge
// iterations -> unroll x2, dual accumulators, 2-deep prefetch.
template <int D>
__device__ __forceinline__ float grpsum(float p) {
#pragma unroll
    for (int m = D / 2; m >= 1; m >>= 1) p += __shfl_xor(p, m, D);
    return p;
}

template <int D, bool LAYER2>
__global__ void gather_attn(const int* __restrict__ rowptr, const int* __restrict__ esrc,
                            const float* __restrict__ q, const float* __restrict__ kv,
                            const float* __restrict__ s,
                            const float* __restrict__ woF,  // [32]=Wo, [32..33]=bo (f32)
                            const int* __restrict__ flags,
                            float* __restrict__ h1, void* __restrict__ out) {
    const int G = 64 / D;  // dst groups per wave
    int lane = threadIdx.x & 63;
    int wave = (blockIdx.x * blockDim.x + threadIdx.x) >> 6;
    int g = lane / D;
    int c = lane % D;
    int dst = wave * G + g;
    if (dst >= N_NODES) return;  // uniform within a D-lane group

    const float rsq = (D == 32) ? 0.17677669529663689f : 0.25f;  // 1/sqrt(D)
    float qc = q[(size_t)dst * D + c];
    int beg = rowptr[dst], end = rowptr[dst + 1];

    float sum0 = 0.0f, sum1 = 0.0f, acc0 = 0.0f, acc1 = 0.0f;

    // 2-deep software pipeline
    int sn0 = (beg < end) ? esrc[beg] : 0;
    int sn1 = (beg + 1 < end) ? esrc[beg + 1] : 0;
    float ka = kv[(size_t)sn0 * 2 * D + c],     va = kv[(size_t)sn0 * 2 * D + D + c];
    float kb = kv[(size_t)sn1 * 2 * D + c],     vb = kv[(size_t)sn1 * 2 * D + D + c];

    for (int e = beg; e < end; e += 2) {
        float kA = ka, vA = va, kB = kb, vB = vb;
        if (e + 2 < end) {
            int sn = esrc[e + 2];
            ka = kv[(size_t)sn * 2 * D + c]; va = kv[(size_t)sn * 2 * D + D + c];
        }
        if (e + 3 < end) {
            int sn = esrc[e + 3];
            kb = kv[(size_t)sn * 2 * D + c]; vb = kv[(size_t)sn * 2 * D + D + c];
        }
        float p0 = grpsum<D>(qc * kA);
        float ex0 = __expf(fminf(fmaxf(p0 * rsq, -80.0f), 80.0f));
        sum0 += ex0; acc0 += vA * ex0;
        if (e + 1 < end) {
            float p1 = grpsum<D>(qc * kB);
            float ex1 = __expf(fminf(fmaxf(p1 * rsq, -80.0f), 80.0f));
            sum1 += ex1; acc1 += vB * ex1;
        }
    }
    float sum = sum0 + sum1, acc = acc0 + acc1;
    float h = acc / (sum + 1e-16f) + s[(size_t)dst * D + c];
    h = h > 0.0f ? h : 0.0f;

    if (!LAYER2) {
        h1[(size_t)dst * D + c] = h;
    } else {
        float p0 = h * woF[c * 2 + 0];
        float p1 = h * woF[c * 2 + 1];
        p0 = grpsum<D>(p0);
        p1 = grpsum<D>(p1);
        if (c == 0) {
            float o0 = p0 + woF[32];
            float o1 = p1 + woF[33];
            if (flags[0]) {
                ((bf16*)out)[dst * 2 + 0] = __float2bfloat16(o0);
                ((bf16*)out)[dst * 2 + 1] = __float2bfloat16(o1);
            } else {
                ((float*)out)[dst * 2 + 0] = o0;
                ((float*)out)[dst * 2 + 1] = o1;
            }
        }
    }
}

extern "C" void kernel_launch(void* const* d_in, const int* in_sizes, int n_in,
                              void* d_out, int out_size, void* d_ws, size_t ws_size,
                              hipStream_t stream) {
    const int* ei  = (const int*)d_in[0];
    const void* emb = d_in[1];
    const void *Wq1 = d_in[2],  *bq1 = d_in[3];
    const void *Wk1 = d_in[4],  *bk1 = d_in[5];
    const void *Wv1 = d_in[6],  *bv1 = d_in[7];
    const void *Ws1 = d_in[8],  *bs1 = d_in[9];
    const void *Wq2 = d_in[10], *bq2 = d_in[11];
    const void *Wk2 = d_in[12], *bk2 = d_in[13];
    const void *Wv2 = d_in[14], *bv2 = d_in[15];
    const void *Ws2 = d_in[16], *bs2 = d_in[17];
    const void *Wo  = d_in[18], *bo  = d_in[19];

    // Workspace layout (floats). embF aliases h1 (embF dead after node_linear L1).
    const size_t ND = (size_t)N_NODES * 32;
    int*   flags  = (int*)d_ws;                   // 64
    float* wp1    = (float*)d_ws + 64;            // 4096
    float* bp1    = wp1 + 4096;                   // 128
    float* wp2    = bp1 + 128;                    // 2048
    float* bp2    = wp2 + 2048;                   // 64
    float* woF    = bp2 + 64;                     // 64
    float* q      = woF + 64;                     // ND
    float* s      = q + ND;                       // ND
    float* kvp    = s + ND;                       // 2*ND
    float* embF   = kvp + 2 * ND;                 // ND (aliased with h1)
    float* h1     = embF;
    int*   deg     = (int*)(embF + ND);           // N_NODES
    int*   cursor  = deg + N_NODES;               // N_NODES
    int*   partial = cursor + N_NODES;            // N_NODES
    int*   rowptr  = partial + N_NODES;           // N_NODES+1
    int*   csums   = rowptr + N_NODES + 1;        // 256
    int*   coffs   = csums + 256;                 // 256
    int*   esrc    = coffs + 256;                 // N_EDGES_C
    // total ~ 72 MB

    const int B = 256;
    const int gNode   = (N_NODES + B - 1) / B;
    const int gZeroI  = (N_NODES + B - 1) / B;
    const int gCast   = (N_NODES * 32 + B - 1) / B;
    const int gNL32   = (N_NODES + 31) / 32;      // NPB=32
    const int gNL16   = (N_NODES + 63) / 64;      // NPB=64
    const int gGat32  = ((N_NODES + 1) / 2 * 64 + B - 1) / B;
    const int gGat16  = ((N_NODES + 3) / 4 * 64 + B - 1) / B;
    const int gSliced = NSLICE * 256;             // 2048 blocks; b%8 = dst slice

    detect_kernel<<<1, 64, 0, stream>>>(emb, ei, flags);
    cast_emb<<<gCast, B, 0, stream>>>(emb, flags, embF, N_NODES * 32);
    cast_params<<<1, B, 0, stream>>>(Wq1, bq1, Wk1, bk1, Wv1, bv1, Ws1, bs1,
                                     Wq2, bq2, Wk2, bk2, Wv2, bv2, Ws2, bs2,
                                     Wo, bo, flags, wp1, bp1, wp2, bp2, woF);

    // ---- CSR build (shared by both layers) ----
    zero_i<<<gZeroI, B, 0, stream>>>(deg, N_NODES);
    hist_deg_sliced<<<gSliced, B, 0, stream>>>(ei, flags, deg);
    scan_chunk<<<N_CHUNKS, SCAN_CHUNK, 0, stream>>>(deg, partial, csums);
    scan_sums<<<1, 256, 0, stream>>>(csums, coffs);
    add_offs<<<gNode, B, 0, stream>>>(partial, coffs, rowptr, cursor);
    scatter_src_sliced<<<gSliced, B, 0, stream>>>(ei, flags, cursor, esrc);

    // ---- Layer 1 (32 -> 32) ----
    node_linear_f32<32><<<gNL32, B, 0, stream>>>(embF, wp1, bp1, q, kvp, s);
    gather_attn<32, false><<<gGat32, B, 0, stream>>>(
        rowptr, esrc, q, kvp, s, woF, flags, h1, nullptr);

    // ---- Layer 2 (32 -> 16) + output linear ----
    node_linear_f32<16><<<gNL16, B, 0, stream>>>(h1, wp2, bp2, q, kvp, s);
    gather_attn<16, true><<<gGat16, B, 0, stream>>>(
        rowptr, esrc, q, kvp, s, woF, flags, nullptr, d_out);
}

// Round 7
// 409.003 us; speedup vs baseline: 11.4060x; 1.1424x over previous
//
#include <hip/hip_runtime.h>
#include <hip/hip_bf16.h>

typedef __hip_bfloat16 bf16;
typedef unsigned int uint;
typedef unsigned short ushort;

#define N_NODES 100000
#define N_EDGES_C 1600000
#define SCAN_CHUNK 512
#define N_CHUNKS ((N_NODES + SCAN_CHUNK - 1) / SCAN_CHUNK)   // 196
#define NSLICE 8                      // XCD count; heuristic blockIdx%8 -> XCD
#define NPS (N_NODES / NSLICE)        // 12500 dsts per slice (exact)

// ---------- runtime dtype helpers (flags[0]=floats-are-bf16, flags[1]=indices-are-int64) ----------
__device__ __forceinline__ float ldf(const void* p, long i, int isbf) {
    return isbf ? __bfloat162float(((const bf16*)p)[i]) : ((const float*)p)[i];
}
__device__ __forceinline__ int ldidx(const int* ei, long pos, int is64) {
    return is64 ? ei[2 * pos] : ei[pos];   // int64 LE: low word at 2*pos
}
__device__ __forceinline__ ushort bfb(float x) {   // f32 -> bf16 bits (RNE)
    bf16 h = __float2bfloat16(x);
    return *(ushort*)&h;
}
__device__ __forceinline__ float bl(uint u) { return __uint_as_float(u << 16); }        // low bf16
__device__ __forceinline__ float bh(uint u) { return __uint_as_float(u & 0xFFFF0000u); } // high bf16

// ---------- dtype detection ----------
__global__ void detect_kernel(const void* emb, const int* ei, int* flags) {
    if (blockIdx.x == 0 && threadIdx.x == 0) {
        const bf16* pb = (const bf16*)emb;
        int big = 0;
        for (int i = 0; i < 256; i++) {
            float v = __bfloat162float(pb[i]);
            if (!(v > -1.0e6f && v < 1.0e6f)) big++;  // f32-viewed-as-bf16 => ~42% huge/nan
        }
        flags[0] = (big <= 8) ? 1 : 0;
        int nz = 0;
        for (int i = 1; i < 256; i += 2) nz += (ei[i] != 0) ? 1 : 0;
        flags[1] = (nz == 0) ? 1 : 0;     // int64 => odd int32 words all zero
    }
}

// ---------- one-time casts to branch-free f32 ----------
__global__ void cast_emb(const void* __restrict__ X, const int* __restrict__ flags,
                         float* __restrict__ XF, int n) {
    int i = blockIdx.x * blockDim.x + threadIdx.x;
    if (i >= n) return;
    XF[i] = ldf(X, i, flags[0]);
}

__global__ void cast_params(
    const void* Wq1, const void* bq1, const void* Wk1, const void* bk1,
    const void* Wv1, const void* bv1, const void* Ws1, const void* bs1,
    const void* Wq2, const void* bq2, const void* Wk2, const void* bk2,
    const void* Wv2, const void* bv2, const void* Ws2, const void* bs2,
    const void* Wo, const void* bo, const int* __restrict__ flags,
    float* __restrict__ wp1, float* __restrict__ bp1,
    float* __restrict__ wp2, float* __restrict__ bp2, float* __restrict__ woF) {
    int isbf = flags[0];
    int t = threadIdx.x;
    for (int i = t; i < 1024; i += 256) {
        wp1[i]        = ldf(Wq1, i, isbf);
        wp1[1024 + i] = ldf(Wk1, i, isbf);
        wp1[2048 + i] = ldf(Wv1, i, isbf);
        wp1[3072 + i] = ldf(Ws1, i, isbf);
    }
    for (int i = t; i < 512; i += 256) {
        wp2[i]        = ldf(Wq2, i, isbf);
        wp2[512 + i]  = ldf(Wk2, i, isbf);
        wp2[1024 + i] = ldf(Wv2, i, isbf);
        wp2[1536 + i] = ldf(Ws2, i, isbf);
    }
    if (t < 32) {
        bp1[t] = ldf(bq1, t, isbf); bp1[32 + t] = ldf(bk1, t, isbf);
        bp1[64 + t] = ldf(bv1, t, isbf); bp1[96 + t] = ldf(bs1, t, isbf);
        woF[t] = ldf(Wo, t, isbf);
    }
    if (t < 16) {
        bp2[t] = ldf(bq2, t, isbf); bp2[16 + t] = ldf(bk2, t, isbf);
        bp2[32 + t] = ldf(bv2, t, isbf); bp2[48 + t] = ldf(bs2, t, isbf);
    }
    if (t < 2) woF[32 + t] = ldf(bo, t, isbf);
}

__global__ void zero_i(int* __restrict__ p, int n) {
    int i = blockIdx.x * blockDim.x + threadIdx.x;
    if (i < n) p[i] = 0;
}

// ---------- CSR build (XCD-sliced: block b handles dst range of slice b%NSLICE) ----------
__global__ void hist_deg_sliced(const int* __restrict__ ei, const int* __restrict__ flags,
                                int* __restrict__ deg) {
    const int is64 = flags[1];
    int slice = blockIdx.x % NSLICE;
    int chunk = blockIdx.x / NSLICE;
    int nchunks = gridDim.x / NSLICE;
    int lo = slice * NPS, hi = lo + NPS;
    for (int e = chunk * blockDim.x + threadIdx.x; e < N_EDGES_C; e += nchunks * blockDim.x) {
        int d = ldidx(ei, (long)N_EDGES_C + e, is64);
        if (d >= lo && d < hi) atomicAdd(&deg[d], 1);
    }
}

__global__ void scatter_src_sliced(const int* __restrict__ ei, const int* __restrict__ flags,
                                   int* __restrict__ cursor, int* __restrict__ esrc) {
    const int is64 = flags[1];
    int slice = blockIdx.x % NSLICE;
    int chunk = blockIdx.x / NSLICE;
    int nchunks = gridDim.x / NSLICE;
    int lo = slice * NPS, hi = lo + NPS;
    for (int e = chunk * blockDim.x + threadIdx.x; e < N_EDGES_C; e += nchunks * blockDim.x) {
        int d = ldidx(ei, (long)N_EDGES_C + e, is64);
        if (d >= lo && d < hi) {
            int s = ldidx(ei, e, is64);
            int pos = atomicAdd(&cursor[d], 1);   // cursor pre-init'd to rowptr
            esrc[pos] = s;
        }
    }
}

__global__ void scan_chunk(const int* __restrict__ deg, int* __restrict__ partial,
                           int* __restrict__ chunkSums) {
    __shared__ int tmp[SCAN_CHUNK];
    int i = blockIdx.x * SCAN_CHUNK + threadIdx.x;
    int v = (i < N_NODES) ? deg[i] : 0;
    tmp[threadIdx.x] = v;
    __syncthreads();
    for (int off = 1; off < SCAN_CHUNK; off <<= 1) {
        int t = (threadIdx.x >= off) ? tmp[threadIdx.x - off] : 0;
        __syncthreads();
        tmp[threadIdx.x] += t;
        __syncthreads();
    }
    if (i < N_NODES) partial[i] = tmp[threadIdx.x] - v;  // exclusive
    if (threadIdx.x == SCAN_CHUNK - 1) chunkSums[blockIdx.x] = tmp[threadIdx.x];
}

__global__ void scan_sums(int* __restrict__ chunkSums, int* __restrict__ chunkOffs) {
    __shared__ int tmp[256];
    int v = (threadIdx.x < N_CHUNKS) ? chunkSums[threadIdx.x] : 0;
    tmp[threadIdx.x] = v;
    __syncthreads();
    for (int off = 1; off < 256; off <<= 1) {
        int t = (threadIdx.x >= off) ? tmp[threadIdx.x - off] : 0;
        __syncthreads();
        tmp[threadIdx.x] += t;
        __syncthreads();
    }
    if (threadIdx.x < N_CHUNKS) chunkOffs[threadIdx.x] = tmp[threadIdx.x] - v;
}

// Writes rowptr AND pre-initializes cursor=rowptr.
__global__ void add_offs(const int* __restrict__ partial, const int* __restrict__ chunkOffs,
                         int* __restrict__ rowptr, int* __restrict__ cursor) {
    int i = blockIdx.x * blockDim.x + threadIdx.x;
    if (i < N_NODES) {
        int r = partial[i] + chunkOffs[i / SCAN_CHUNK];
        rowptr[i] = r;
        cursor[i] = r;
    }
    if (i == 0) rowptr[N_NODES] = N_EDGES_C;
}

// ---------- node linears (branch-free f32 in, kv packed bf16 out) ----------
// q,s f32; kvb[n] = [k(0..D-1) | v(0..D-1)] bf16 -> one 128B (D=32) / 64B (D=16) line.
template <int DOUT>
__global__ void node_linear_f32(const float* __restrict__ X,      // [N,32] f32
                                const float* __restrict__ wpack,  // [4][32][DOUT] f32
                                const float* __restrict__ bpack,  // [4][DOUT] f32
                                float* __restrict__ q, ushort* __restrict__ kvb,
                                float* __restrict__ s) {
    const int TPN = DOUT / 4;     // threads per node (8 or 4)
    const int NPB = 256 / TPN;    // nodes per block (32 or 64)
    const int W_ELEMS = 4 * 32 * DOUT;
    __shared__ float sW[W_ELEMS];
    __shared__ float sb[4 * DOUT];
    __shared__ float sX[NPB * 36];  // pad stride 36 (16B-aligned, conflict-free)

    const float4* wp4 = (const float4*)wpack;
    float4* sW4 = (float4*)sW;
    for (int i = threadIdx.x; i < W_ELEMS / 4; i += 256) sW4[i] = wp4[i];
    if (threadIdx.x < 4 * DOUT) sb[threadIdx.x] = bpack[threadIdx.x];
    const int base = blockIdx.x * NPB * 32;
    for (int i = threadIdx.x; i < NPB * 32; i += 256) {
        int g = base + i;
        sX[(i >> 5) * 36 + (i & 31)] = (g < N_NODES * 32) ? X[g] : 0.0f;
    }
    __syncthreads();

    int l = threadIdx.x / TPN;
    int c4 = (threadIdx.x % TPN) * 4;
    int n = blockIdx.x * NPB + l;
    if (n >= N_NODES) return;

    float xr[32];
#pragma unroll
    for (int j = 0; j < 8; j++) {
        float4 t = *(const float4*)&sX[l * 36 + 4 * j];
        xr[4 * j] = t.x; xr[4 * j + 1] = t.y; xr[4 * j + 2] = t.z; xr[4 * j + 3] = t.w;
    }
    float acc[4][4];
#pragma unroll
    for (int m = 0; m < 4; m++)
#pragma unroll
        for (int j = 0; j < 4; j++) acc[m][j] = sb[m * DOUT + c4 + j];

#pragma unroll
    for (int t = 0; t < 32; t++) {
#pragma unroll
        for (int m = 0; m < 4; m++) {
            float4 w = *(const float4*)&sW[(m * 32 + t) * DOUT + c4];
            acc[m][0] += xr[t] * w.x;
            acc[m][1] += xr[t] * w.y;
            acc[m][2] += xr[t] * w.z;
            acc[m][3] += xr[t] * w.w;
        }
    }
    size_t o = (size_t)n * DOUT + c4;
    *(float4*)&q[o] = make_float4(acc[0][0], acc[0][1], acc[0][2], acc[0][3]);
    *(float4*)&s[o] = make_float4(acc[3][0], acc[3][1], acc[3][2], acc[3][3]);
    size_t okv = (size_t)n * 2 * DOUT + c4;
    ushort4 kp = make_ushort4(bfb(acc[1][0]), bfb(acc[1][1]), bfb(acc[1][2]), bfb(acc[1][3]));
    ushort4 vp = make_ushort4(bfb(acc[2][0]), bfb(acc[2][1]), bfb(acc[2][2]), bfb(acc[2][3]));
    *(ushort4*)&kvb[okv]        = kp;
    *(ushort4*)&kvb[okv + DOUT] = vp;
}

// ---------- fused gather attention (bf16 kv, D/2 lanes per dst, no-max softmax) ----------
// Lane owns dims (2c, 2c+1) as bf16x2 words; one 128B line per edge (D=32).
template <int D, bool LAYER2>
__global__ void gather_attn(const int* __restrict__ rowptr, const int* __restrict__ esrc,
                            const float* __restrict__ q, const ushort* __restrict__ kvb,
                            const float* __restrict__ s,
                            const float* __restrict__ woF,  // [32]=Wo, [32..33]=bo (f32)
                            const int* __restrict__ flags,
                            float* __restrict__ h1o, void* __restrict__ out) {
    const int LPD = D / 2;   // lanes per dst (16 or 8)
    const int G = 64 / LPD;  // dst groups per wave (4 or 8)
    int lane = threadIdx.x & 63;
    int wave = (blockIdx.x * blockDim.x + threadIdx.x) >> 6;
    int g = lane / LPD;
    int c = lane % LPD;      // dims 2c, 2c+1
    int dst = wave * G + g;
    if (dst >= N_NODES) return;  // uniform within a group; shfl stays in-group

    const float rsq = (D == 32) ? 0.17677669529663689f : 0.25f;  // 1/sqrt(D)
    float2 qc = *(const float2*)(q + (size_t)dst * D + 2 * c);
    int beg = rowptr[dst], end = rowptr[dst + 1];

    const char* kvbase = (const char*)kvb;
    const int ROW = 4 * D;            // row bytes: [k bf16 x D | v bf16 x D]
    const int koff = 4 * c;
    const int voff = 2 * D + 4 * c;

    float sum0 = 0.f, sum1 = 0.f;
    float a00 = 0.f, a01 = 0.f, a10 = 0.f, a11 = 0.f;

    // 2-deep software pipeline, unroll x2
    int sn0 = (beg < end) ? esrc[beg] : 0;
    int sn1 = (beg + 1 < end) ? esrc[beg + 1] : 0;
    const char* pa = kvbase + (size_t)sn0 * ROW;
    const char* pb = kvbase + (size_t)sn1 * ROW;
    uint kau = *(const uint*)(pa + koff), vau = *(const uint*)(pa + voff);
    uint kbu = *(const uint*)(pb + koff), vbu = *(const uint*)(pb + voff);

    for (int e = beg; e < end; e += 2) {
        uint kA = kau, vA = vau, kB = kbu, vB = vbu;
        if (e + 2 < end) {
            const char* p = kvbase + (size_t)esrc[e + 2] * ROW;
            kau = *(const uint*)(p + koff); vau = *(const uint*)(p + voff);
        }
        if (e + 3 < end) {
            const char* p = kvbase + (size_t)esrc[e + 3] * ROW;
            kbu = *(const uint*)(p + koff); vbu = *(const uint*)(p + voff);
        }
        float pd = qc.x * bl(kA) + qc.y * bh(kA);
#pragma unroll
        for (int m = LPD / 2; m >= 1; m >>= 1) pd += __shfl_xor(pd, m, LPD);
        float ex = __expf(fminf(fmaxf(pd * rsq, -80.0f), 80.0f));
        sum0 += ex; a00 += bl(vA) * ex; a01 += bh(vA) * ex;
        if (e + 1 < end) {
            float pd1 = qc.x * bl(kB) + qc.y * bh(kB);
#pragma unroll
            for (int m = LPD / 2; m >= 1; m >>= 1) pd1 += __shfl_xor(pd1, m, LPD);
            float ex1 = __expf(fminf(fmaxf(pd1 * rsq, -80.0f), 80.0f));
            sum1 += ex1; a10 += bl(vB) * ex1; a11 += bh(vB) * ex1;
        }
    }
    float inv = 1.0f / (sum0 + sum1 + 1e-16f);
    float2 sc = *(const float2*)(s + (size_t)dst * D + 2 * c);
    float h0 = (a00 + a10) * inv + sc.x; h0 = h0 > 0.0f ? h0 : 0.0f;
    float h1 = (a01 + a11) * inv + sc.y; h1 = h1 > 0.0f ? h1 : 0.0f;

    if (!LAYER2) {
        *(float2*)(h1o + (size_t)dst * D + 2 * c) = make_float2(h0, h1);
    } else {
        float p0 = h0 * woF[4 * c + 0] + h1 * woF[4 * c + 2];
        float p1 = h0 * woF[4 * c + 1] + h1 * woF[4 * c + 3];
#pragma unroll
        for (int m = LPD / 2; m >= 1; m >>= 1) {
            p0 += __shfl_xor(p0, m, LPD);
            p1 += __shfl_xor(p1, m, LPD);
        }
        if (c == 0) {
            float o0 = p0 + woF[32];
            float o1 = p1 + woF[33];
            if (flags[0]) {
                ((bf16*)out)[dst * 2 + 0] = __float2bfloat16(o0);
                ((bf16*)out)[dst * 2 + 1] = __float2bfloat16(o1);
            } else {
                ((float*)out)[dst * 2 + 0] = o0;
                ((float*)out)[dst * 2 + 1] = o1;
            }
        }
    }
}

extern "C" void kernel_launch(void* const* d_in, const int* in_sizes, int n_in,
                              void* d_out, int out_size, void* d_ws, size_t ws_size,
                              hipStream_t stream) {
    const int* ei  = (const int*)d_in[0];
    const void* emb = d_in[1];
    const void *Wq1 = d_in[2],  *bq1 = d_in[3];
    const void *Wk1 = d_in[4],  *bk1 = d_in[5];
    const void *Wv1 = d_in[6],  *bv1 = d_in[7];
    const void *Ws1 = d_in[8],  *bs1 = d_in[9];
    const void *Wq2 = d_in[10], *bq2 = d_in[11];
    const void *Wk2 = d_in[12], *bk2 = d_in[13];
    const void *Wv2 = d_in[14], *bv2 = d_in[15];
    const void *Ws2 = d_in[16], *bs2 = d_in[17];
    const void *Wo  = d_in[18], *bo  = d_in[19];

    // Workspace layout (floats). embF aliases h1 (embF dead after node_linear L1).
    const size_t ND = (size_t)N_NODES * 32;
    int*   flags  = (int*)d_ws;                   // 64
    float* wp1    = (float*)d_ws + 64;            // 4096
    float* bp1    = wp1 + 4096;                   // 128
    float* wp2    = bp1 + 128;                    // 2048
    float* bp2    = wp2 + 2048;                   // 64
    float* woF    = bp2 + 64;                     // 64
    float* q      = woF + 64;                     // ND
    float* s      = q + ND;                       // ND
    ushort* kvb   = (ushort*)(s + ND);            // 2*ND ushorts = ND floats
    float* embF   = (float*)(kvb + 2 * ND);       // ND (aliased with h1)
    float* h1     = embF;
    int*   deg     = (int*)(embF + ND);           // N_NODES
    int*   cursor  = deg + N_NODES;               // N_NODES
    int*   partial = cursor + N_NODES;            // N_NODES
    int*   rowptr  = partial + N_NODES;           // N_NODES+1
    int*   csums   = rowptr + N_NODES + 1;        // 256
    int*   coffs   = csums + 256;                 // 256
    int*   esrc    = coffs + 256;                 // N_EDGES_C
    // total ~ 4*12.8MB + 8.2MB ~ 60MB

    const int B = 256;
    const int gNode   = (N_NODES + B - 1) / B;
    const int gZeroI  = (N_NODES + B - 1) / B;
    const int gCast   = (N_NODES * 32 + B - 1) / B;
    const int gNL32   = (N_NODES + 31) / 32;      // NPB=32
    const int gNL16   = (N_NODES + 63) / 64;      // NPB=64
    // gather: G=4 dsts/wave (D=32) -> 25000 waves; G=8 (D=16) -> 12500 waves
    const int gGat32  = ((N_NODES + 3) / 4 * 64 + B - 1) / B;
    const int gGat16  = ((N_NODES + 7) / 8 * 64 + B - 1) / B;
    const int gSliced = NSLICE * 256;             // 2048 blocks; b%8 = dst slice

    detect_kernel<<<1, 64, 0, stream>>>(emb, ei, flags);
    cast_emb<<<gCast, B, 0, stream>>>(emb, flags, embF, N_NODES * 32);
    cast_params<<<1, B, 0, stream>>>(Wq1, bq1, Wk1, bk1, Wv1, bv1, Ws1, bs1,
                                     Wq2, bq2, Wk2, bk2, Wv2, bv2, Ws2, bs2,
                                     Wo, bo, flags, wp1, bp1, wp2, bp2, woF);

    // ---- CSR build (shared by both layers) ----
    zero_i<<<gZeroI, B, 0, stream>>>(deg, N_NODES);
    hist_deg_sliced<<<gSliced, B, 0, stream>>>(ei, flags, deg);
    scan_chunk<<<N_CHUNKS, SCAN_CHUNK, 0, stream>>>(deg, partial, csums);
    scan_sums<<<1, 256, 0, stream>>>(csums, coffs);
    add_offs<<<gNode, B, 0, stream>>>(partial, coffs, rowptr, cursor);
    scatter_src_sliced<<<gSliced, B, 0, stream>>>(ei, flags, cursor, esrc);

    // ---- Layer 1 (32 -> 32) ----
    node_linear_f32<32><<<gNL32, B, 0, stream>>>(embF, wp1, bp1, q, kvb, s);
    gather_attn<32, false><<<gGat32, B, 0, stream>>>(
        rowptr, esrc, q, kvb, s, woF, flags, h1, nullptr);

    // ---- Layer 2 (32 -> 16) + output linear ----
    node_linear_f32<16><<<gNL16, B, 0, stream>>>(h1, wp2, bp2, q, kvb, s);
    gather_attn<16, true><<<gGat16, B, 0, stream>>>(
        rowptr, esrc, q, kvb, s, woF, flags, nullptr, d_out);
}

// Round 8
// 344.530 us; speedup vs baseline: 13.5404x; 1.1871x over previous
//
#include <hip/hip_runtime.h>
#include <hip/hip_bf16.h>

typedef __hip_bfloat16 bf16;
typedef unsigned int uint;
typedef unsigned short ushort;

#define N_NODES 100000
#define N_EDGES_C 1600000
#define NBKT 3125          // buckets of 32 dsts: 3125*32 = 100000 exactly
#define BCAP 128           // pairs per (bucket, replica): mean 64, +8 sigma
#define CAPT (8 * BCAP)    // 1024 pairs per bucket total
#define NREP 8             // replicas ~ XCDs (blockIdx%8 heuristic)

// ---------- runtime dtype helpers (flags[0]=floats-are-bf16, flags[1]=indices-are-int64) ----------
__device__ __forceinline__ float ldf(const void* p, long i, int isbf) {
    return isbf ? __bfloat162float(((const bf16*)p)[i]) : ((const float*)p)[i];
}
__device__ __forceinline__ int ldidx(const int* ei, long pos, int is64) {
    return is64 ? ei[2 * pos] : ei[pos];   // int64 LE: low word at 2*pos
}
__device__ __forceinline__ ushort bfb(float x) {   // f32 -> bf16 bits (RNE)
    bf16 h = __float2bfloat16(x);
    return *(ushort*)&h;
}
__device__ __forceinline__ float bl(uint u) { return __uint_as_float(u << 16); }        // low bf16
__device__ __forceinline__ float bh(uint u) { return __uint_as_float(u & 0xFFFF0000u); } // high bf16

// ---------- dtype detection ----------
__global__ void detect_kernel(const void* emb, const int* ei, int* flags) {
    if (blockIdx.x == 0 && threadIdx.x == 0) {
        const bf16* pb = (const bf16*)emb;
        int big = 0;
        for (int i = 0; i < 256; i++) {
            float v = __bfloat162float(pb[i]);
            if (!(v > -1.0e6f && v < 1.0e6f)) big++;  // f32-viewed-as-bf16 => ~42% huge/nan
        }
        flags[0] = (big <= 8) ? 1 : 0;
        int nz = 0;
        for (int i = 1; i < 256; i += 2) nz += (ei[i] != 0) ? 1 : 0;
        flags[1] = (nz == 0) ? 1 : 0;     // int64 => odd int32 words all zero
    }
}

// ---------- one-time casts to branch-free f32 ----------
__global__ void cast_emb(const void* __restrict__ X, const int* __restrict__ flags,
                         float* __restrict__ XF, int n) {
    int i = blockIdx.x * blockDim.x + threadIdx.x;
    if (i >= n) return;
    XF[i] = ldf(X, i, flags[0]);
}

__global__ void cast_params(
    const void* Wq1, const void* bq1, const void* Wk1, const void* bk1,
    const void* Wv1, const void* bv1, const void* Ws1, const void* bs1,
    const void* Wq2, const void* bq2, const void* Wk2, const void* bk2,
    const void* Wv2, const void* bv2, const void* Ws2, const void* bs2,
    const void* Wo, const void* bo, const int* __restrict__ flags,
    float* __restrict__ wp1, float* __restrict__ bp1,
    float* __restrict__ wp2, float* __restrict__ bp2, float* __restrict__ woF) {
    int isbf = flags[0];
    int t = threadIdx.x;
    for (int i = t; i < 1024; i += 256) {
        wp1[i]        = ldf(Wq1, i, isbf);
        wp1[1024 + i] = ldf(Wk1, i, isbf);
        wp1[2048 + i] = ldf(Wv1, i, isbf);
        wp1[3072 + i] = ldf(Ws1, i, isbf);
    }
    for (int i = t; i < 512; i += 256) {
        wp2[i]        = ldf(Wq2, i, isbf);
        wp2[512 + i]  = ldf(Wk2, i, isbf);
        wp2[1024 + i] = ldf(Wv2, i, isbf);
        wp2[1536 + i] = ldf(Ws2, i, isbf);
    }
    if (t < 32) {
        bp1[t] = ldf(bq1, t, isbf); bp1[32 + t] = ldf(bk1, t, isbf);
        bp1[64 + t] = ldf(bv1, t, isbf); bp1[96 + t] = ldf(bs1, t, isbf);
        woF[t] = ldf(Wo, t, isbf);
    }
    if (t < 16) {
        bp2[t] = ldf(bq2, t, isbf); bp2[16 + t] = ldf(bk2, t, isbf);
        bp2[32 + t] = ldf(bv2, t, isbf); bp2[48 + t] = ldf(bs2, t, isbf);
    }
    if (t < 2) woF[32 + t] = ldf(bo, t, isbf);
}

__global__ void zero_i(int* __restrict__ p, int n) {
    int i = blockIdx.x * blockDim.x + threadIdx.x;
    if (i < n) p[i] = 0;
}

// ---------- Phase 1: single-pass bucket scatter of (src,dst) pairs ----------
// Edge list is read exactly once (coalesced). Pairs land in bucket (dst>>5),
// replica blockIdx%8 (heuristic XCD), at atomicAdd position. Replaces
// hist + scan + per-dst scatter (3 passes) with one pass.
__global__ void bucket_scatter(const int* __restrict__ ei, const int* __restrict__ flags,
                               int* __restrict__ cur, uint2* __restrict__ pairs) {
    const int is64 = flags[1];
    int rep = blockIdx.x & (NREP - 1);
    long stride = (long)gridDim.x * blockDim.x;
    for (long e = (long)blockIdx.x * blockDim.x + threadIdx.x; e < N_EDGES_C; e += stride) {
        int d = ldidx(ei, (long)N_EDGES_C + e, is64);
        int s = ldidx(ei, e, is64);
        int b = d >> 5;
        int pos = atomicAdd(&cur[rep * NBKT + b], 1);
        if (pos < BCAP)   // overflow statistically impossible (+8 sigma); clamp for safety
            pairs[((size_t)b * NREP + rep) * BCAP + pos] = make_uint2((uint)s, (uint)d);
    }
}

// ---------- Phase 2: per-bucket exact CSR build, fully in LDS ----------
// One block per bucket (32 dsts). esrc layout is gap-tolerant: bucket b owns
// esrc[b*CAPT .. b*CAPT+total); gather uses rowbeg/rowend (not rowptr[d+1]).
__global__ void bucket_build(const int* __restrict__ cur, const uint2* __restrict__ pairs,
                             int* __restrict__ esrc,
                             int* __restrict__ rowbeg, int* __restrict__ rowend) {
    __shared__ uint2 P[CAPT];          // 8 KB
    __shared__ int E[CAPT];            // 4 KB
    __shared__ int scnt[NREP], soff[NREP + 1];
    __shared__ int dcnt[32], dexcl[32], dcur[32];
    int b = blockIdx.x;
    int t = threadIdx.x;
    if (t < NREP) scnt[t] = min(cur[t * NBKT + b], BCAP);
    if (t < 32) { dcnt[t] = 0; dcur[t] = 0; }
    __syncthreads();
    if (t == 0) {
        int o = 0;
        for (int r = 0; r < NREP; r++) { soff[r] = o; o += scnt[r]; }
        soff[NREP] = o;
    }
    __syncthreads();
    for (int r = 0; r < NREP; r++) {
        int c = scnt[r];
        for (int i = t; i < c; i += 256)
            P[soff[r] + i] = pairs[((size_t)b * NREP + r) * BCAP + i];
    }
    __syncthreads();
    int tot = soff[NREP];
    for (int i = t; i < tot; i += 256) atomicAdd(&dcnt[P[i].y & 31], 1);
    __syncthreads();
    if (t == 0) {
        int o = 0;
        for (int j = 0; j < 32; j++) { dexcl[j] = o; o += dcnt[j]; }
    }
    __syncthreads();
    const int EB = b * CAPT;
    if (t < 32) {
        rowbeg[b * 32 + t] = EB + dexcl[t];
        rowend[b * 32 + t] = EB + dexcl[t] + dcnt[t];
    }
    for (int i = t; i < tot; i += 256) {
        int j = P[i].y & 31;
        int p = dexcl[j] + atomicAdd(&dcur[j], 1);
        E[p] = (int)P[i].x;
    }
    __syncthreads();
    for (int i = t; i < tot; i += 256) esrc[EB + i] = E[i];  // coalesced 64B lines
}

// ---------- node linears (branch-free f32 in, kv packed bf16 out) ----------
template <int DOUT>
__global__ void node_linear_f32(const float* __restrict__ X,      // [N,32] f32
                                const float* __restrict__ wpack,  // [4][32][DOUT] f32
                                const float* __restrict__ bpack,  // [4][DOUT] f32
                                float* __restrict__ q, ushort* __restrict__ kvb,
                                float* __restrict__ s) {
    const int TPN = DOUT / 4;     // threads per node (8 or 4)
    const int NPB = 256 / TPN;    // nodes per block (32 or 64)
    const int W_ELEMS = 4 * 32 * DOUT;
    __shared__ float sW[W_ELEMS];
    __shared__ float sb[4 * DOUT];
    __shared__ float sX[NPB * 36];  // pad stride 36 (16B-aligned, conflict-free)

    const float4* wp4 = (const float4*)wpack;
    float4* sW4 = (float4*)sW;
    for (int i = threadIdx.x; i < W_ELEMS / 4; i += 256) sW4[i] = wp4[i];
    if (threadIdx.x < 4 * DOUT) sb[threadIdx.x] = bpack[threadIdx.x];
    const int base = blockIdx.x * NPB * 32;
    for (int i = threadIdx.x; i < NPB * 32; i += 256) {
        int g = base + i;
        sX[(i >> 5) * 36 + (i & 31)] = (g < N_NODES * 32) ? X[g] : 0.0f;
    }
    __syncthreads();

    int l = threadIdx.x / TPN;
    int c4 = (threadIdx.x % TPN) * 4;
    int n = blockIdx.x * NPB + l;
    if (n >= N_NODES) return;

    float xr[32];
#pragma unroll
    for (int j = 0; j < 8; j++) {
        float4 t = *(const float4*)&sX[l * 36 + 4 * j];
        xr[4 * j] = t.x; xr[4 * j + 1] = t.y; xr[4 * j + 2] = t.z; xr[4 * j + 3] = t.w;
    }
    float acc[4][4];
#pragma unroll
    for (int m = 0; m < 4; m++)
#pragma unroll
        for (int j = 0; j < 4; j++) acc[m][j] = sb[m * DOUT + c4 + j];

#pragma unroll
    for (int t = 0; t < 32; t++) {
#pragma unroll
        for (int m = 0; m < 4; m++) {
            float4 w = *(const float4*)&sW[(m * 32 + t) * DOUT + c4];
            acc[m][0] += xr[t] * w.x;
            acc[m][1] += xr[t] * w.y;
            acc[m][2] += xr[t] * w.z;
            acc[m][3] += xr[t] * w.w;
        }
    }
    size_t o = (size_t)n * DOUT + c4;
    *(float4*)&q[o] = make_float4(acc[0][0], acc[0][1], acc[0][2], acc[0][3]);
    *(float4*)&s[o] = make_float4(acc[3][0], acc[3][1], acc[3][2], acc[3][3]);
    size_t okv = (size_t)n * 2 * DOUT + c4;
    ushort4 kp = make_ushort4(bfb(acc[1][0]), bfb(acc[1][1]), bfb(acc[1][2]), bfb(acc[1][3]));
    ushort4 vp = make_ushort4(bfb(acc[2][0]), bfb(acc[2][1]), bfb(acc[2][2]), bfb(acc[2][3]));
    *(ushort4*)&kvb[okv]        = kp;
    *(ushort4*)&kvb[okv + DOUT] = vp;
}

// ---------- fused gather attention (bf16 kv, D/2 lanes per dst, no-max softmax) ----------
template <int D, bool LAYER2>
__global__ void gather_attn(const int* __restrict__ rowbeg, const int* __restrict__ rowend,
                            const int* __restrict__ esrc,
                            const float* __restrict__ q, const ushort* __restrict__ kvb,
                            const float* __restrict__ s,
                            const float* __restrict__ woF,  // [32]=Wo, [32..33]=bo (f32)
                            const int* __restrict__ flags,
                            float* __restrict__ h1o, void* __restrict__ out) {
    const int LPD = D / 2;   // lanes per dst (16 or 8)
    const int G = 64 / LPD;  // dst groups per wave (4 or 8)
    int lane = threadIdx.x & 63;
    int wave = (blockIdx.x * blockDim.x + threadIdx.x) >> 6;
    int g = lane / LPD;
    int c = lane % LPD;      // dims 2c, 2c+1
    int dst = wave * G + g;
    if (dst >= N_NODES) return;  // uniform within a group; shfl stays in-group

    const float rsq = (D == 32) ? 0.17677669529663689f : 0.25f;  // 1/sqrt(D)
    float2 qc = *(const float2*)(q + (size_t)dst * D + 2 * c);
    int beg = rowbeg[dst], end = rowend[dst];

    const char* kvbase = (const char*)kvb;
    const int ROW = 4 * D;            // row bytes: [k bf16 x D | v bf16 x D]
    const int koff = 4 * c;
    const int voff = 2 * D + 4 * c;

    float sum0 = 0.f, sum1 = 0.f;
    float a00 = 0.f, a01 = 0.f, a10 = 0.f, a11 = 0.f;

    // 2-deep software pipeline, unroll x2
    int sn0 = (beg < end) ? esrc[beg] : 0;
    int sn1 = (beg + 1 < end) ? esrc[beg + 1] : 0;
    const char* pa = kvbase + (size_t)sn0 * ROW;
    const char* pb = kvbase + (size_t)sn1 * ROW;
    uint kau = *(const uint*)(pa + koff), vau = *(const uint*)(pa + voff);
    uint kbu = *(const uint*)(pb + koff), vbu = *(const uint*)(pb + voff);

    for (int e = beg; e < end; e += 2) {
        uint kA = kau, vA = vau, kB = kbu, vB = vbu;
        if (e + 2 < end) {
            const char* p = kvbase + (size_t)esrc[e + 2] * ROW;
            kau = *(const uint*)(p + koff); vau = *(const uint*)(p + voff);
        }
        if (e + 3 < end) {
            const char* p = kvbase + (size_t)esrc[e + 3] * ROW;
            kbu = *(const uint*)(p + koff); vbu = *(const uint*)(p + voff);
        }
        float pd = qc.x * bl(kA) + qc.y * bh(kA);
#pragma unroll
        for (int m = LPD / 2; m >= 1; m >>= 1) pd += __shfl_xor(pd, m, LPD);
        float ex = __expf(fminf(fmaxf(pd * rsq, -80.0f), 80.0f));
        sum0 += ex; a00 += bl(vA) * ex; a01 += bh(vA) * ex;
        if (e + 1 < end) {
            float pd1 = qc.x * bl(kB) + qc.y * bh(kB);
#pragma unroll
            for (int m = LPD / 2; m >= 1; m >>= 1) pd1 += __shfl_xor(pd1, m, LPD);
            float ex1 = __expf(fminf(fmaxf(pd1 * rsq, -80.0f), 80.0f));
            sum1 += ex1; a10 += bl(vB) * ex1; a11 += bh(vB) * ex1;
        }
    }
    float inv = 1.0f / (sum0 + sum1 + 1e-16f);
    float2 sc = *(const float2*)(s + (size_t)dst * D + 2 * c);
    float h0 = (a00 + a10) * inv + sc.x; h0 = h0 > 0.0f ? h0 : 0.0f;
    float h1 = (a01 + a11) * inv + sc.y; h1 = h1 > 0.0f ? h1 : 0.0f;

    if (!LAYER2) {
        *(float2*)(h1o + (size_t)dst * D + 2 * c) = make_float2(h0, h1);
    } else {
        float p0 = h0 * woF[4 * c + 0] + h1 * woF[4 * c + 2];
        float p1 = h0 * woF[4 * c + 1] + h1 * woF[4 * c + 3];
#pragma unroll
        for (int m = LPD / 2; m >= 1; m >>= 1) {
            p0 += __shfl_xor(p0, m, LPD);
            p1 += __shfl_xor(p1, m, LPD);
        }
        if (c == 0) {
            float o0 = p0 + woF[32];
            float o1 = p1 + woF[33];
            if (flags[0]) {
                ((bf16*)out)[dst * 2 + 0] = __float2bfloat16(o0);
                ((bf16*)out)[dst * 2 + 1] = __float2bfloat16(o1);
            } else {
                ((float*)out)[dst * 2 + 0] = o0;
                ((float*)out)[dst * 2 + 1] = o1;
            }
        }
    }
}

extern "C" void kernel_launch(void* const* d_in, const int* in_sizes, int n_in,
                              void* d_out, int out_size, void* d_ws, size_t ws_size,
                              hipStream_t stream) {
    const int* ei  = (const int*)d_in[0];
    const void* emb = d_in[1];
    const void *Wq1 = d_in[2],  *bq1 = d_in[3];
    const void *Wk1 = d_in[4],  *bk1 = d_in[5];
    const void *Wv1 = d_in[6],  *bv1 = d_in[7];
    const void *Ws1 = d_in[8],  *bs1 = d_in[9];
    const void *Wq2 = d_in[10], *bq2 = d_in[11];
    const void *Wk2 = d_in[12], *bk2 = d_in[13];
    const void *Wv2 = d_in[14], *bv2 = d_in[15];
    const void *Ws2 = d_in[16], *bs2 = d_in[17];
    const void *Wo  = d_in[18], *bo  = d_in[19];

    // Workspace layout (floats). Aliasing:
    //   pairs (25.6MB) aliases q+s (live ranges: pairs dead after bucket_build,
    //   q/s first written by node_linear which runs after).
    //   embF aliases h1 (embF dead after NL1; h1 written by gather1 after).
    const size_t ND = (size_t)N_NODES * 32;
    float* base   = (float*)d_ws;
    int*   flags  = (int*)base;                    // 64
    float* wp1    = base + 64;                     // 4096
    float* bp1    = wp1 + 4096;                    // 128
    float* wp2    = bp1 + 128;                     // 2048
    float* bp2    = wp2 + 2048;                    // 64
    float* woF    = bp2 + 64;                      // 64
    int*   cur    = (int*)(woF + 64);              // NREP*NBKT = 25000 -> pad 25088
    int*   rowbeg = cur + 25088;                   // N_NODES
    int*   rowend = rowbeg + N_NODES;              // N_NODES
    float* uni    = (float*)(rowend + N_NODES);    // union start (16B aligned: offset mult of 4)
    uint2* pairs  = (uint2*)uni;                   // NBKT*NREP*BCAP uint2 = 6.4M floats
    float* q      = uni;                           // ND (alias pairs[0:ND])
    float* s      = uni + ND;                      // ND (alias pairs[ND:2ND])
    ushort* kvb   = (ushort*)(uni + 2 * ND);       // 2*ND ushorts = ND floats
    float* embF   = uni + 3 * ND;                  // ND (aliased with h1)
    float* h1     = embF;
    int*   esrc   = (int*)(uni + 4 * ND);          // NBKT*CAPT = 3.2M ints
    // total ~ (225k + 5*3.2M) floats ~ 65 MB

    const int B = 256;
    const int gCast   = (N_NODES * 32 + B - 1) / B;
    const int gZeroI  = (25088 + B - 1) / B;
    const int gNL32   = (N_NODES + 31) / 32;      // NPB=32
    const int gNL16   = (N_NODES + 63) / 64;      // NPB=64
    const int gGat32  = ((N_NODES + 3) / 4 * 64 + B - 1) / B;
    const int gGat16  = ((N_NODES + 7) / 8 * 64 + B - 1) / B;

    detect_kernel<<<1, 64, 0, stream>>>(emb, ei, flags);
    cast_emb<<<gCast, B, 0, stream>>>(emb, flags, embF, N_NODES * 32);
    cast_params<<<1, B, 0, stream>>>(Wq1, bq1, Wk1, bk1, Wv1, bv1, Ws1, bs1,
                                     Wq2, bq2, Wk2, bk2, Wv2, bv2, Ws2, bs2,
                                     Wo, bo, flags, wp1, bp1, wp2, bp2, woF);

    // ---- CSR build via 2-phase bucket sort (shared by both layers) ----
    zero_i<<<gZeroI, B, 0, stream>>>(cur, 25088);
    bucket_scatter<<<2048, B, 0, stream>>>(ei, flags, cur, pairs);
    bucket_build<<<NBKT, B, 0, stream>>>(cur, pairs, esrc, rowbeg, rowend);

    // ---- Layer 1 (32 -> 32) ----
    node_linear_f32<32><<<gNL32, B, 0, stream>>>(embF, wp1, bp1, q, kvb, s);
    gather_attn<32, false><<<gGat32, B, 0, stream>>>(
        rowbeg, rowend, esrc, q, kvb, s, woF, flags, h1, nullptr);

    // ---- Layer 2 (32 -> 16) + output linear ----
    node_linear_f32<16><<<gNL16, B, 0, stream>>>(h1, wp2, bp2, q, kvb, s);
    gather_attn<16, true><<<gGat16, B, 0, stream>>>(
        rowbeg, rowend, esrc, q, kvb, s, woF, flags, nullptr, d_out);
}

// Round 9
// 344.193 us; speedup vs baseline: 13.5537x; 1.0010x over previous
//
#include <hip/hip_runtime.h>
#include <hip/hip_bf16.h>

typedef __hip_bfloat16 bf16;
typedef unsigned int uint;
typedef unsigned short ushort;

#define N_NODES 100000
#define N_EDGES_C 1600000
#define NBKT 3125          // buckets of 32 dsts: 3125*32 = 100000 exactly
#define BCAP 128           // pairs per (bucket, replica): mean 64, +8 sigma
#define CAPT (8 * BCAP)    // 1024 pairs per bucket total
#define NREP 8             // replicas ~ XCDs (blockIdx%8 heuristic)

// ---------- runtime dtype helpers (flags[0]=floats-are-bf16, flags[1]=indices-are-int64) ----------
__device__ __forceinline__ float ldf(const void* p, long i, int isbf) {
    return isbf ? __bfloat162float(((const bf16*)p)[i]) : ((const float*)p)[i];
}
__device__ __forceinline__ int ldidx(const int* ei, long pos, int is64) {
    return is64 ? ei[2 * pos] : ei[pos];   // int64 LE: low word at 2*pos
}
__device__ __forceinline__ ushort bfb(float x) {   // f32 -> bf16 bits (RNE)
    bf16 h = __float2bfloat16(x);
    return *(ushort*)&h;
}
__device__ __forceinline__ float bl(uint u) { return __uint_as_float(u << 16); }        // low bf16
__device__ __forceinline__ float bh(uint u) { return __uint_as_float(u & 0xFFFF0000u); } // high bf16

// ---------- dtype detection ----------
__global__ void detect_kernel(const void* emb, const int* ei, int* flags) {
    if (blockIdx.x == 0 && threadIdx.x == 0) {
        const bf16* pb = (const bf16*)emb;
        int big = 0;
        for (int i = 0; i < 256; i++) {
            float v = __bfloat162float(pb[i]);
            if (!(v > -1.0e6f && v < 1.0e6f)) big++;  // f32-viewed-as-bf16 => ~42% huge/nan
        }
        flags[0] = (big <= 8) ? 1 : 0;
        int nz = 0;
        for (int i = 1; i < 256; i += 2) nz += (ei[i] != 0) ? 1 : 0;
        flags[1] = (nz == 0) ? 1 : 0;     // int64 => odd int32 words all zero
    }
}

// ---------- one-time casts to branch-free f32 ----------
__global__ void cast_emb(const void* __restrict__ X, const int* __restrict__ flags,
                         float* __restrict__ XF, int n) {
    int i = blockIdx.x * blockDim.x + threadIdx.x;
    if (i >= n) return;
    XF[i] = ldf(X, i, flags[0]);
}

__global__ void cast_params(
    const void* Wq1, const void* bq1, const void* Wk1, const void* bk1,
    const void* Wv1, const void* bv1, const void* Ws1, const void* bs1,
    const void* Wq2, const void* bq2, const void* Wk2, const void* bk2,
    const void* Wv2, const void* bv2, const void* Ws2, const void* bs2,
    const void* Wo, const void* bo, const int* __restrict__ flags,
    float* __restrict__ wp1, float* __restrict__ bp1,
    float* __restrict__ wp2, float* __restrict__ bp2, float* __restrict__ woF) {
    int isbf = flags[0];
    int t = threadIdx.x;
    for (int i = t; i < 1024; i += 256) {
        wp1[i]        = ldf(Wq1, i, isbf);
        wp1[1024 + i] = ldf(Wk1, i, isbf);
        wp1[2048 + i] = ldf(Wv1, i, isbf);
        wp1[3072 + i] = ldf(Ws1, i, isbf);
    }
    for (int i = t; i < 512; i += 256) {
        wp2[i]        = ldf(Wq2, i, isbf);
        wp2[512 + i]  = ldf(Wk2, i, isbf);
        wp2[1024 + i] = ldf(Wv2, i, isbf);
        wp2[1536 + i] = ldf(Ws2, i, isbf);
    }
    if (t < 32) {
        bp1[t] = ldf(bq1, t, isbf); bp1[32 + t] = ldf(bk1, t, isbf);
        bp1[64 + t] = ldf(bv1, t, isbf); bp1[96 + t] = ldf(bs1, t, isbf);
        woF[t] = ldf(Wo, t, isbf);
    }
    if (t < 16) {
        bp2[t] = ldf(bq2, t, isbf); bp2[16 + t] = ldf(bk2, t, isbf);
        bp2[32 + t] = ldf(bv2, t, isbf); bp2[48 + t] = ldf(bs2, t, isbf);
    }
    if (t < 2) woF[32 + t] = ldf(bo, t, isbf);
}

__global__ void zero_i(int* __restrict__ p, int n) {
    int i = blockIdx.x * blockDim.x + threadIdx.x;
    if (i < n) p[i] = 0;
}

// ---------- Phase 1: single-pass bucket scatter of packed (src | (dst&31)<<17) ----------
// Edge list read exactly once (coalesced). 4B per edge (src<2^17, local-dst 5 bits):
// half the store bytes/lines of uint2 pairs. Replica = blockIdx%8 (heuristic XCD)
// keeps each sub-region's lines written from one XCD.
__global__ void bucket_scatter(const int* __restrict__ ei, const int* __restrict__ flags,
                               int* __restrict__ cur, uint* __restrict__ pairs) {
    const int is64 = flags[1];
    int rep = blockIdx.x & (NREP - 1);
    long stride = (long)gridDim.x * blockDim.x;
    for (long e = (long)blockIdx.x * blockDim.x + threadIdx.x; e < N_EDGES_C; e += stride) {
        int d = ldidx(ei, (long)N_EDGES_C + e, is64);
        int s = ldidx(ei, e, is64);
        int b = d >> 5;
        uint pk = (uint)s | ((uint)(d & 31) << 17);
        int pos = atomicAdd(&cur[rep * NBKT + b], 1);
        if (pos < BCAP)   // overflow statistically impossible (+8 sigma); clamp for safety
            pairs[((size_t)b * NREP + rep) * BCAP + pos] = pk;
    }
}

// ---------- Phase 2: per-bucket exact CSR build, fully in LDS ----------
// One block per bucket (32 dsts). esrc layout is gap-tolerant: bucket b owns
// esrc[b*CAPT .. b*CAPT+total); gather uses rowbeg/rowend.
__global__ void bucket_build(const int* __restrict__ cur, const uint* __restrict__ pairs,
                             int* __restrict__ esrc,
                             int* __restrict__ rowbeg, int* __restrict__ rowend) {
    __shared__ uint P[CAPT];           // 4 KB
    __shared__ int E[CAPT];            // 4 KB
    __shared__ int scnt[NREP], soff[NREP + 1];
    __shared__ int dcnt[32], dexcl[32], dcur[32];
    int b = blockIdx.x;
    int t = threadIdx.x;
    if (t < NREP) scnt[t] = min(cur[t * NBKT + b], BCAP);
    if (t < 32) { dcnt[t] = 0; dcur[t] = 0; }
    __syncthreads();
    if (t == 0) {
        int o = 0;
        for (int r = 0; r < NREP; r++) { soff[r] = o; o += scnt[r]; }
        soff[NREP] = o;
    }
    __syncthreads();
    for (int r = 0; r < NREP; r++) {
        int c = scnt[r];
        for (int i = t; i < c; i += 256)
            P[soff[r] + i] = pairs[((size_t)b * NREP + r) * BCAP + i];
    }
    __syncthreads();
    int tot = soff[NREP];
    for (int i = t; i < tot; i += 256) atomicAdd(&dcnt[(P[i] >> 17) & 31], 1);
    __syncthreads();
    if (t == 0) {
        int o = 0;
        for (int j = 0; j < 32; j++) { dexcl[j] = o; o += dcnt[j]; }
    }
    __syncthreads();
    const int EB = b * CAPT;
    if (t < 32) {
        rowbeg[b * 32 + t] = EB + dexcl[t];
        rowend[b * 32 + t] = EB + dexcl[t] + dcnt[t];
    }
    for (int i = t; i < tot; i += 256) {
        uint pk = P[i];
        int j = (pk >> 17) & 31;
        int p = dexcl[j] + atomicAdd(&dcur[j], 1);
        E[p] = (int)(pk & 0x1FFFF);
    }
    __syncthreads();
    for (int i = t; i < tot; i += 256) esrc[EB + i] = E[i];  // coalesced 64B lines
}

// ---------- node linears (branch-free f32 in, kv packed bf16 out) ----------
template <int DOUT>
__global__ void node_linear_f32(const float* __restrict__ X,      // [N,32] f32
                                const float* __restrict__ wpack,  // [4][32][DOUT] f32
                                const float* __restrict__ bpack,  // [4][DOUT] f32
                                float* __restrict__ q, ushort* __restrict__ kvb,
                                float* __restrict__ s) {
    const int TPN = DOUT / 4;     // threads per node (8 or 4)
    const int NPB = 256 / TPN;    // nodes per block (32 or 64)
    const int W_ELEMS = 4 * 32 * DOUT;
    __shared__ float sW[W_ELEMS];
    __shared__ float sb[4 * DOUT];
    __shared__ float sX[NPB * 36];  // pad stride 36 (16B-aligned, conflict-free)

    const float4* wp4 = (const float4*)wpack;
    float4* sW4 = (float4*)sW;
    for (int i = threadIdx.x; i < W_ELEMS / 4; i += 256) sW4[i] = wp4[i];
    if (threadIdx.x < 4 * DOUT) sb[threadIdx.x] = bpack[threadIdx.x];
    const int base = blockIdx.x * NPB * 32;
    for (int i = threadIdx.x; i < NPB * 32; i += 256) {
        int g = base + i;
        sX[(i >> 5) * 36 + (i & 31)] = (g < N_NODES * 32) ? X[g] : 0.0f;
    }
    __syncthreads();

    int l = threadIdx.x / TPN;
    int c4 = (threadIdx.x % TPN) * 4;
    int n = blockIdx.x * NPB + l;
    if (n >= N_NODES) return;

    float xr[32];
#pragma unroll
    for (int j = 0; j < 8; j++) {
        float4 t = *(const float4*)&sX[l * 36 + 4 * j];
        xr[4 * j] = t.x; xr[4 * j + 1] = t.y; xr[4 * j + 2] = t.z; xr[4 * j + 3] = t.w;
    }
    float acc[4][4];
#pragma unroll
    for (int m = 0; m < 4; m++)
#pragma unroll
        for (int j = 0; j < 4; j++) acc[m][j] = sb[m * DOUT + c4 + j];

#pragma unroll
    for (int t = 0; t < 32; t++) {
#pragma unroll
        for (int m = 0; m < 4; m++) {
            float4 w = *(const float4*)&sW[(m * 32 + t) * DOUT + c4];
            acc[m][0] += xr[t] * w.x;
            acc[m][1] += xr[t] * w.y;
            acc[m][2] += xr[t] * w.z;
            acc[m][3] += xr[t] * w.w;
        }
    }
    size_t o = (size_t)n * DOUT + c4;
    *(float4*)&q[o] = make_float4(acc[0][0], acc[0][1], acc[0][2], acc[0][3]);
    *(float4*)&s[o] = make_float4(acc[3][0], acc[3][1], acc[3][2], acc[3][3]);
    size_t okv = (size_t)n * 2 * DOUT + c4;
    ushort4 kp = make_ushort4(bfb(acc[1][0]), bfb(acc[1][1]), bfb(acc[1][2]), bfb(acc[1][3]));
    ushort4 vp = make_ushort4(bfb(acc[2][0]), bfb(acc[2][1]), bfb(acc[2][2]), bfb(acc[2][3]));
    *(ushort4*)&kvb[okv]        = kp;
    *(ushort4*)&kvb[okv + DOUT] = vp;
}

// ---------- fused gather attention (bf16 kv, D/2 lanes per dst, no-max softmax) ----------
template <int D, bool LAYER2>
__global__ void gather_attn(const int* __restrict__ rowbeg, const int* __restrict__ rowend,
                            const int* __restrict__ esrc,
                            const float* __restrict__ q, const ushort* __restrict__ kvb,
                            const float* __restrict__ s,
                            const float* __restrict__ woF,  // [32]=Wo, [32..33]=bo (f32)
                            const int* __restrict__ flags,
                            float* __restrict__ h1o, void* __restrict__ out) {
    const int LPD = D / 2;   // lanes per dst (16 or 8)
    const int G = 64 / LPD;  // dst groups per wave (4 or 8)
    int lane = threadIdx.x & 63;
    int wave = (blockIdx.x * blockDim.x + threadIdx.x) >> 6;
    int g = lane / LPD;
    int c = lane % LPD;      // dims 2c, 2c+1
    int dst = wave * G + g;
    if (dst >= N_NODES) return;  // uniform within a group; shfl stays in-group

    const float rsq = (D == 32) ? 0.17677669529663689f : 0.25f;  // 1/sqrt(D)
    float2 qc = *(const float2*)(q + (size_t)dst * D + 2 * c);
    int beg = rowbeg[dst], end = rowend[dst];

    const char* kvbase = (const char*)kvb;
    const int ROW = 4 * D;            // row bytes: [k bf16 x D | v bf16 x D]
    const int koff = 4 * c;
    const int voff = 2 * D + 4 * c;

    float sum0 = 0.f, sum1 = 0.f;
    float a00 = 0.f, a01 = 0.f, a10 = 0.f, a11 = 0.f;

    // 2-deep software pipeline, unroll x2
    int sn0 = (beg < end) ? esrc[beg] : 0;
    int sn1 = (beg + 1 < end) ? esrc[beg + 1] : 0;
    const char* pa = kvbase + (size_t)sn0 * ROW;
    const char* pb = kvbase + (size_t)sn1 * ROW;
    uint kau = *(const uint*)(pa + koff), vau = *(const uint*)(pa + voff);
    uint kbu = *(const uint*)(pb + koff), vbu = *(const uint*)(pb + voff);

    for (int e = beg; e < end; e += 2) {
        uint kA = kau, vA = vau, kB = kbu, vB = vbu;
        if (e + 2 < end) {
            const char* p = kvbase + (size_t)esrc[e + 2] * ROW;
            kau = *(const uint*)(p + koff); vau = *(const uint*)(p + voff);
        }
        if (e + 3 < end) {
            const char* p = kvbase + (size_t)esrc[e + 3] * ROW;
            kbu = *(const uint*)(p + koff); vbu = *(const uint*)(p + voff);
        }
        float pd = qc.x * bl(kA) + qc.y * bh(kA);
#pragma unroll
        for (int m = LPD / 2; m >= 1; m >>= 1) pd += __shfl_xor(pd, m, LPD);
        float ex = __expf(fminf(fmaxf(pd * rsq, -80.0f), 80.0f));
        sum0 += ex; a00 += bl(vA) * ex; a01 += bh(vA) * ex;
        if (e + 1 < end) {
            float pd1 = qc.x * bl(kB) + qc.y * bh(kB);
#pragma unroll
            for (int m = LPD / 2; m >= 1; m >>= 1) pd1 += __shfl_xor(pd1, m, LPD);
            float ex1 = __expf(fminf(fmaxf(pd1 * rsq, -80.0f), 80.0f));
            sum1 += ex1; a10 += bl(vB) * ex1; a11 += bh(vB) * ex1;
        }
    }
    float inv = 1.0f / (sum0 + sum1 + 1e-16f);
    float2 sc = *(const float2*)(s + (size_t)dst * D + 2 * c);
    float h0 = (a00 + a10) * inv + sc.x; h0 = h0 > 0.0f ? h0 : 0.0f;
    float h1 = (a01 + a11) * inv + sc.y; h1 = h1 > 0.0f ? h1 : 0.0f;

    if (!LAYER2) {
        *(float2*)(h1o + (size_t)dst * D + 2 * c) = make_float2(h0, h1);
    } else {
        float p0 = h0 * woF[4 * c + 0] + h1 * woF[4 * c + 2];
        float p1 = h0 * woF[4 * c + 1] + h1 * woF[4 * c + 3];
#pragma unroll
        for (int m = LPD / 2; m >= 1; m >>= 1) {
            p0 += __shfl_xor(p0, m, LPD);
            p1 += __shfl_xor(p1, m, LPD);
        }
        if (c == 0) {
            float o0 = p0 + woF[32];
            float o1 = p1 + woF[33];
            if (flags[0]) {
                ((bf16*)out)[dst * 2 + 0] = __float2bfloat16(o0);
                ((bf16*)out)[dst * 2 + 1] = __float2bfloat16(o1);
            } else {
                ((float*)out)[dst * 2 + 0] = o0;
                ((float*)out)[dst * 2 + 1] = o1;
            }
        }
    }
}

extern "C" void kernel_launch(void* const* d_in, const int* in_sizes, int n_in,
                              void* d_out, int out_size, void* d_ws, size_t ws_size,
                              hipStream_t stream) {
    const int* ei  = (const int*)d_in[0];
    const void* emb = d_in[1];
    const void *Wq1 = d_in[2],  *bq1 = d_in[3];
    const void *Wk1 = d_in[4],  *bk1 = d_in[5];
    const void *Wv1 = d_in[6],  *bv1 = d_in[7];
    const void *Ws1 = d_in[8],  *bs1 = d_in[9];
    const void *Wq2 = d_in[10], *bq2 = d_in[11];
    const void *Wk2 = d_in[12], *bk2 = d_in[13];
    const void *Wv2 = d_in[14], *bv2 = d_in[15];
    const void *Ws2 = d_in[16], *bs2 = d_in[17];
    const void *Wo  = d_in[18], *bo  = d_in[19];

    // Workspace layout (floats). Aliasing:
    //   pairs (12.8MB now) aliases q (pairs dead after bucket_build; q written after).
    //   embF aliases h1 (embF dead after NL1; h1 written by gather1 after).
    const size_t ND = (size_t)N_NODES * 32;
    float* base   = (float*)d_ws;
    int*   flags  = (int*)base;                    // 64
    float* wp1    = base + 64;                     // 4096
    float* bp1    = wp1 + 4096;                    // 128
    float* wp2    = bp1 + 128;                     // 2048
    float* bp2    = wp2 + 2048;                    // 64
    float* woF    = bp2 + 64;                      // 64
    int*   cur    = (int*)(woF + 64);              // NREP*NBKT = 25000 -> pad 25088
    int*   rowbeg = cur + 25088;                   // N_NODES
    int*   rowend = rowbeg + N_NODES;              // N_NODES
    float* uni    = (float*)(rowend + N_NODES);    // union start
    uint*  pairs  = (uint*)uni;                    // NBKT*NREP*BCAP uints = 3.2M
    float* q      = uni;                           // ND (alias pairs)
    float* s      = uni + ND;                      // ND
    ushort* kvb   = (ushort*)(uni + 2 * ND);       // 2*ND ushorts = ND floats
    float* embF   = uni + 3 * ND;                  // ND (aliased with h1)
    float* h1     = embF;
    int*   esrc   = (int*)(uni + 4 * ND);          // NBKT*CAPT = 3.2M ints
    // total ~ (225k + 5*3.2M) floats ~ 65 MB

    const int B = 256;
    const int gCast   = (N_NODES * 32 + B - 1) / B;
    const int gZeroI  = (25088 + B - 1) / B;
    const int gNL32   = (N_NODES + 31) / 32;      // NPB=32
    const int gNL16   = (N_NODES + 63) / 64;      // NPB=64
    const int gGat32  = ((N_NODES + 3) / 4 * 64 + B - 1) / B;
    const int gGat16  = ((N_NODES + 7) / 8 * 64 + B - 1) / B;

    detect_kernel<<<1, 64, 0, stream>>>(emb, ei, flags);
    cast_emb<<<gCast, B, 0, stream>>>(emb, flags, embF, N_NODES * 32);
    cast_params<<<1, B, 0, stream>>>(Wq1, bq1, Wk1, bk1, Wv1, bv1, Ws1, bs1,
                                     Wq2, bq2, Wk2, bk2, Wv2, bv2, Ws2, bs2,
                                     Wo, bo, flags, wp1, bp1, wp2, bp2, woF);

    // ---- CSR build via 2-phase bucket sort (shared by both layers) ----
    zero_i<<<gZeroI, B, 0, stream>>>(cur, 25088);
    bucket_scatter<<<4096, B, 0, stream>>>(ei, flags, cur, pairs);
    bucket_build<<<NBKT, B, 0, stream>>>(cur, pairs, esrc, rowbeg, rowend);

    // ---- Layer 1 (32 -> 32) ----
    node_linear_f32<32><<<gNL32, B, 0, stream>>>(embF, wp1, bp1, q, kvb, s);
    gather_attn<32, false><<<gGat32, B, 0, stream>>>(
        rowbeg, rowend, esrc, q, kvb, s, woF, flags, h1, nullptr);

    // ---- Layer 2 (32 -> 16) + output linear ----
    node_linear_f32<16><<<gNL16, B, 0, stream>>>(h1, wp2, bp2, q, kvb, s);
    gather_attn<16, true><<<gGat16, B, 0, stream>>>(
        rowbeg, rowend, esrc, q, kvb, s, woF, flags, nullptr, d_out);
}

// Round 10
// 306.018 us; speedup vs baseline: 15.2444x; 1.1247x over previous
//
#include <hip/hip_runtime.h>
#include <hip/hip_bf16.h>

typedef __hip_bfloat16 bf16;
typedef unsigned int uint;
typedef unsigned short ushort;

#define N_NODES 100000
#define N_EDGES_C 1600000
#define NSB 196            // super-buckets: dst>>9 (512 dsts each); 196*512=100352
#define NSBP 200           // padded counter array size
#define SBCAP 10240        // per-SB region capacity (mean 8163, +23 sigma)
#define RND 4096           // edges per radix_a block

// ---------- runtime dtype helpers (flags[0]=floats-are-bf16, flags[1]=indices-are-int64) ----------
__device__ __forceinline__ float ldf(const void* p, long i, int isbf) {
    return isbf ? __bfloat162float(((const bf16*)p)[i]) : ((const float*)p)[i];
}
__device__ __forceinline__ int ldidx(const int* ei, long pos, int is64) {
    return is64 ? ei[2 * pos] : ei[pos];   // int64 LE: low word at 2*pos
}
__device__ __forceinline__ ushort bfb(float x) {   // f32 -> bf16 bits (RNE)
    bf16 h = __float2bfloat16(x);
    return *(ushort*)&h;
}
__device__ __forceinline__ float bl(uint u) { return __uint_as_float(u << 16); }        // low bf16
__device__ __forceinline__ float bh(uint u) { return __uint_as_float(u & 0xFFFF0000u); } // high bf16

// ---------- dtype detection ----------
__global__ void detect_kernel(const void* emb, const int* ei, int* flags) {
    if (blockIdx.x == 0 && threadIdx.x == 0) {
        const bf16* pb = (const bf16*)emb;
        int big = 0;
        for (int i = 0; i < 256; i++) {
            float v = __bfloat162float(pb[i]);
            if (!(v > -1.0e6f && v < 1.0e6f)) big++;  // f32-viewed-as-bf16 => ~42% huge/nan
        }
        flags[0] = (big <= 8) ? 1 : 0;
        int nz = 0;
        for (int i = 1; i < 256; i += 2) nz += (ei[i] != 0) ? 1 : 0;
        flags[1] = (nz == 0) ? 1 : 0;     // int64 => odd int32 words all zero
    }
}

// ---------- one-time casts to branch-free f32 ----------
__global__ void cast_emb(const void* __restrict__ X, const int* __restrict__ flags,
                         float* __restrict__ XF, int n) {
    int i = blockIdx.x * blockDim.x + threadIdx.x;
    if (i >= n) return;
    XF[i] = ldf(X, i, flags[0]);
}

__global__ void cast_params(
    const void* Wq1, const void* bq1, const void* Wk1, const void* bk1,
    const void* Wv1, const void* bv1, const void* Ws1, const void* bs1,
    const void* Wq2, const void* bq2, const void* Wk2, const void* bk2,
    const void* Wv2, const void* bv2, const void* Ws2, const void* bs2,
    const void* Wo, const void* bo, const int* __restrict__ flags,
    float* __restrict__ wp1, float* __restrict__ bp1,
    float* __restrict__ wp2, float* __restrict__ bp2, float* __restrict__ woF) {
    int isbf = flags[0];
    int t = threadIdx.x;
    for (int i = t; i < 1024; i += 256) {
        wp1[i]        = ldf(Wq1, i, isbf);
        wp1[1024 + i] = ldf(Wk1, i, isbf);
        wp1[2048 + i] = ldf(Wv1, i, isbf);
        wp1[3072 + i] = ldf(Ws1, i, isbf);
    }
    for (int i = t; i < 512; i += 256) {
        wp2[i]        = ldf(Wq2, i, isbf);
        wp2[512 + i]  = ldf(Wk2, i, isbf);
        wp2[1024 + i] = ldf(Wv2, i, isbf);
        wp2[1536 + i] = ldf(Ws2, i, isbf);
    }
    if (t < 32) {
        bp1[t] = ldf(bq1, t, isbf); bp1[32 + t] = ldf(bk1, t, isbf);
        bp1[64 + t] = ldf(bv1, t, isbf); bp1[96 + t] = ldf(bs1, t, isbf);
        woF[t] = ldf(Wo, t, isbf);
    }
    if (t < 16) {
        bp2[t] = ldf(bq2, t, isbf); bp2[16 + t] = ldf(bk2, t, isbf);
        bp2[32 + t] = ldf(bv2, t, isbf); bp2[48 + t] = ldf(bs2, t, isbf);
    }
    if (t < 2) woF[32 + t] = ldf(bo, t, isbf);
}

__global__ void zero_i(int* __restrict__ p, int n) {
    int i = blockIdx.x * blockDim.x + threadIdx.x;
    if (i < n) p[i] = 0;
}

// ---------- Pass A: LDS-coalesced radix into 196 super-buckets ----------
// Each block sorts a 4096-edge round by SB in LDS, then flushes contiguous runs
// (avg ~21 elements) to per-SB global regions. Global atomics: ~150/block (vs 1/edge).
// Packed edge: src (17 bits) | (dst & 511) << 17.
__global__ void radix_a(const int* __restrict__ ei, const int* __restrict__ flags,
                        int* __restrict__ curSB, uint* __restrict__ pairsSB) {
    __shared__ int cnt[NSBP];
    __shared__ int excl[NSBP];
    __shared__ int gbase[NSBP];
    __shared__ uint sVal[RND];
    __shared__ unsigned char sSb[RND];
    const int is64 = flags[1];
    int t = threadIdx.x;
    for (int i = t; i < NSBP; i += 256) cnt[i] = 0;
    __syncthreads();
    long base = (long)blockIdx.x * RND;

    int mySb[16]; int myRank[16]; uint myPk[16];
#pragma unroll
    for (int r = 0; r < 16; r++) {
        long e = base + r * 256 + t;
        mySb[r] = -1;
        if (e < N_EDGES_C) {
            int d = ldidx(ei, (long)N_EDGES_C + e, is64);
            int s = ldidx(ei, e, is64);
            int sb = d >> 9;
            myPk[r] = (uint)s | ((uint)(d & 511) << 17);
            myRank[r] = atomicAdd(&cnt[sb], 1);
            mySb[r] = sb;
        }
    }
    __syncthreads();
    if (t == 0) {
        int o = 0;
        for (int i = 0; i < NSBP; i++) { excl[i] = o; o += cnt[i]; }
    }
    __syncthreads();
#pragma unroll
    for (int r = 0; r < 16; r++) {
        if (mySb[r] >= 0) {
            int pos = excl[mySb[r]] + myRank[r];
            sVal[pos] = myPk[r];
            sSb[pos] = (unsigned char)mySb[r];
        }
    }
    __syncthreads();
    for (int i = t; i < NSBP; i += 256)
        gbase[i] = (cnt[i] > 0) ? atomicAdd(&curSB[i], cnt[i]) : 0;
    __syncthreads();
    int tot = excl[NSBP - 1] + cnt[NSBP - 1];
    for (int i = t; i < tot; i += 256) {   // consecutive i in a run -> consecutive global addr
        int sb = sSb[i];
        int gp = gbase[sb] + (i - excl[sb]);
        if (gp < SBCAP)
            pairsSB[(size_t)sb * SBCAP + gp] = sVal[i];
    }
}

// ---------- Pass B: per-SB CSR build (512 dsts) ----------
// Loads its region into LDS, counts/scans local dsts, writes rowbeg/rowend and
// scatters esrc within a single 40KB window (single-CU burst -> single-XCD L2).
__global__ void radix_b(const int* __restrict__ curSB, const uint* __restrict__ pairsSB,
                        int* __restrict__ esrc,
                        int* __restrict__ rowbeg, int* __restrict__ rowend) {
    __shared__ uint sP[SBCAP];                 // 40 KB
    __shared__ int dcnt[512], dexcl[512], dcur[512];
    int sb = blockIdx.x;
    int t = threadIdx.x;
    int n = min(curSB[sb], SBCAP);
    for (int i = t; i < 512; i += 256) { dcnt[i] = 0; dcur[i] = 0; }
    __syncthreads();
    for (int i = t; i < n; i += 256) {
        uint pk = pairsSB[(size_t)sb * SBCAP + i];
        sP[i] = pk;
        atomicAdd(&dcnt[(pk >> 17) & 511], 1);
    }
    __syncthreads();
    if (t == 0) {
        int o = 0;
        for (int j = 0; j < 512; j++) { dexcl[j] = o; o += dcnt[j]; }
    }
    __syncthreads();
    const int EB = sb * SBCAP;
    for (int j = t; j < 512; j += 256) {
        int dst = sb * 512 + j;
        if (dst < N_NODES) {
            rowbeg[dst] = EB + dexcl[j];
            rowend[dst] = EB + dexcl[j] + dcnt[j];
        }
    }
    for (int i = t; i < n; i += 256) {
        uint pk = sP[i];
        int j = (pk >> 17) & 511;
        int p = dexcl[j] + atomicAdd(&dcur[j], 1);
        esrc[EB + p] = (int)(pk & 0x1FFFF);
    }
}

// ---------- node linears (branch-free f32 in, kv packed bf16 out) ----------
template <int DOUT>
__global__ void node_linear_f32(const float* __restrict__ X,      // [N,32] f32
                                const float* __restrict__ wpack,  // [4][32][DOUT] f32
                                const float* __restrict__ bpack,  // [4][DOUT] f32
                                float* __restrict__ q, ushort* __restrict__ kvb,
                                float* __restrict__ s) {
    const int TPN = DOUT / 4;     // threads per node (8 or 4)
    const int NPB = 256 / TPN;    // nodes per block (32 or 64)
    const int W_ELEMS = 4 * 32 * DOUT;
    __shared__ float sW[W_ELEMS];
    __shared__ float sb[4 * DOUT];
    __shared__ float sX[NPB * 36];  // pad stride 36 (16B-aligned, conflict-free)

    const float4* wp4 = (const float4*)wpack;
    float4* sW4 = (float4*)sW;
    for (int i = threadIdx.x; i < W_ELEMS / 4; i += 256) sW4[i] = wp4[i];
    if (threadIdx.x < 4 * DOUT) sb[threadIdx.x] = bpack[threadIdx.x];
    const int base = blockIdx.x * NPB * 32;
    for (int i = threadIdx.x; i < NPB * 32; i += 256) {
        int g = base + i;
        sX[(i >> 5) * 36 + (i & 31)] = (g < N_NODES * 32) ? X[g] : 0.0f;
    }
    __syncthreads();

    int l = threadIdx.x / TPN;
    int c4 = (threadIdx.x % TPN) * 4;
    int n = blockIdx.x * NPB + l;
    if (n >= N_NODES) return;

    float xr[32];
#pragma unroll
    for (int j = 0; j < 8; j++) {
        float4 t = *(const float4*)&sX[l * 36 + 4 * j];
        xr[4 * j] = t.x; xr[4 * j + 1] = t.y; xr[4 * j + 2] = t.z; xr[4 * j + 3] = t.w;
    }
    float acc[4][4];
#pragma unroll
    for (int m = 0; m < 4; m++)
#pragma unroll
        for (int j = 0; j < 4; j++) acc[m][j] = sb[m * DOUT + c4 + j];

#pragma unroll
    for (int t = 0; t < 32; t++) {
#pragma unroll
        for (int m = 0; m < 4; m++) {
            float4 w = *(const float4*)&sW[(m * 32 + t) * DOUT + c4];
            acc[m][0] += xr[t] * w.x;
            acc[m][1] += xr[t] * w.y;
            acc[m][2] += xr[t] * w.z;
            acc[m][3] += xr[t] * w.w;
        }
    }
    size_t o = (size_t)n * DOUT + c4;
    *(float4*)&q[o] = make_float4(acc[0][0], acc[0][1], acc[0][2], acc[0][3]);
    *(float4*)&s[o] = make_float4(acc[3][0], acc[3][1], acc[3][2], acc[3][3]);
    size_t okv = (size_t)n * 2 * DOUT + c4;
    ushort4 kp = make_ushort4(bfb(acc[1][0]), bfb(acc[1][1]), bfb(acc[1][2]), bfb(acc[1][3]));
    ushort4 vp = make_ushort4(bfb(acc[2][0]), bfb(acc[2][1]), bfb(acc[2][2]), bfb(acc[2][3]));
    *(ushort4*)&kvb[okv]        = kp;
    *(ushort4*)&kvb[okv + DOUT] = vp;
}

// ---------- fused gather attention (bf16 kv, D/2 lanes per dst, no-max softmax) ----------
template <int D, bool LAYER2>
__global__ void gather_attn(const int* __restrict__ rowbeg, const int* __restrict__ rowend,
                            const int* __restrict__ esrc,
                            const float* __restrict__ q, const ushort* __restrict__ kvb,
                            const float* __restrict__ s,
                            const float* __restrict__ woF,  // [32]=Wo, [32..33]=bo (f32)
                            const int* __restrict__ flags,
                            float* __restrict__ h1o, void* __restrict__ out) {
    const int LPD = D / 2;   // lanes per dst (16 or 8)
    const int G = 64 / LPD;  // dst groups per wave (4 or 8)
    int lane = threadIdx.x & 63;
    int wave = (blockIdx.x * blockDim.x + threadIdx.x) >> 6;
    int g = lane / LPD;
    int c = lane % LPD;      // dims 2c, 2c+1
    int dst = wave * G + g;
    if (dst >= N_NODES) return;  // uniform within a group; shfl stays in-group

    const float rsq = (D == 32) ? 0.17677669529663689f : 0.25f;  // 1/sqrt(D)
    float2 qc = *(const float2*)(q + (size_t)dst * D + 2 * c);
    int beg = rowbeg[dst], end = rowend[dst];

    const char* kvbase = (const char*)kvb;
    const int ROW = 4 * D;            // row bytes: [k bf16 x D | v bf16 x D]
    const int koff = 4 * c;
    const int voff = 2 * D + 4 * c;

    float sum0 = 0.f, sum1 = 0.f;
    float a00 = 0.f, a01 = 0.f, a10 = 0.f, a11 = 0.f;

    // 2-deep software pipeline, unroll x2
    int sn0 = (beg < end) ? esrc[beg] : 0;
    int sn1 = (beg + 1 < end) ? esrc[beg + 1] : 0;
    const char* pa = kvbase + (size_t)sn0 * ROW;
    const char* pb = kvbase + (size_t)sn1 * ROW;
    uint kau = *(const uint*)(pa + koff), vau = *(const uint*)(pa + voff);
    uint kbu = *(const uint*)(pb + koff), vbu = *(const uint*)(pb + voff);

    for (int e = beg; e < end; e += 2) {
        uint kA = kau, vA = vau, kB = kbu, vB = vbu;
        if (e + 2 < end) {
            const char* p = kvbase + (size_t)esrc[e + 2] * ROW;
            kau = *(const uint*)(p + koff); vau = *(const uint*)(p + voff);
        }
        if (e + 3 < end) {
            const char* p = kvbase + (size_t)esrc[e + 3] * ROW;
            kbu = *(const uint*)(p + koff); vbu = *(const uint*)(p + voff);
        }
        float pd = qc.x * bl(kA) + qc.y * bh(kA);
#pragma unroll
        for (int m = LPD / 2; m >= 1; m >>= 1) pd += __shfl_xor(pd, m, LPD);
        float ex = __expf(fminf(fmaxf(pd * rsq, -80.0f), 80.0f));
        sum0 += ex; a00 += bl(vA) * ex; a01 += bh(vA) * ex;
        if (e + 1 < end) {
            float pd1 = qc.x * bl(kB) + qc.y * bh(kB);
#pragma unroll
            for (int m = LPD / 2; m >= 1; m >>= 1) pd1 += __shfl_xor(pd1, m, LPD);
            float ex1 = __expf(fminf(fmaxf(pd1 * rsq, -80.0f), 80.0f));
            sum1 += ex1; a10 += bl(vB) * ex1; a11 += bh(vB) * ex1;
        }
    }
    float inv = 1.0f / (sum0 + sum1 + 1e-16f);
    float2 sc = *(const float2*)(s + (size_t)dst * D + 2 * c);
    float h0 = (a00 + a10) * inv + sc.x; h0 = h0 > 0.0f ? h0 : 0.0f;
    float h1 = (a01 + a11) * inv + sc.y; h1 = h1 > 0.0f ? h1 : 0.0f;

    if (!LAYER2) {
        *(float2*)(h1o + (size_t)dst * D + 2 * c) = make_float2(h0, h1);
    } else {
        float p0 = h0 * woF[4 * c + 0] + h1 * woF[4 * c + 2];
        float p1 = h0 * woF[4 * c + 1] + h1 * woF[4 * c + 3];
#pragma unroll
        for (int m = LPD / 2; m >= 1; m >>= 1) {
            p0 += __shfl_xor(p0, m, LPD);
            p1 += __shfl_xor(p1, m, LPD);
        }
        if (c == 0) {
            float o0 = p0 + woF[32];
            float o1 = p1 + woF[33];
            if (flags[0]) {
                ((bf16*)out)[dst * 2 + 0] = __float2bfloat16(o0);
                ((bf16*)out)[dst * 2 + 1] = __float2bfloat16(o1);
            } else {
                ((float*)out)[dst * 2 + 0] = o0;
                ((float*)out)[dst * 2 + 1] = o1;
            }
        }
    }
}

extern "C" void kernel_launch(void* const* d_in, const int* in_sizes, int n_in,
                              void* d_out, int out_size, void* d_ws, size_t ws_size,
                              hipStream_t stream) {
    const int* ei  = (const int*)d_in[0];
    const void* emb = d_in[1];
    const void *Wq1 = d_in[2],  *bq1 = d_in[3];
    const void *Wk1 = d_in[4],  *bk1 = d_in[5];
    const void *Wv1 = d_in[6],  *bv1 = d_in[7];
    const void *Ws1 = d_in[8],  *bs1 = d_in[9];
    const void *Wq2 = d_in[10], *bq2 = d_in[11];
    const void *Wk2 = d_in[12], *bk2 = d_in[13];
    const void *Wv2 = d_in[14], *bv2 = d_in[15];
    const void *Ws2 = d_in[16], *bs2 = d_in[17];
    const void *Wo  = d_in[18], *bo  = d_in[19];

    // Workspace layout (floats). Aliasing:
    //   pairsSB (8MB) aliases q (pairsSB dead after radix_b; q written after by NL).
    //   embF aliases h1 (embF dead after NL1; h1 written by gather1 after).
    const size_t ND = (size_t)N_NODES * 32;
    const size_t SBTOT = (size_t)NSB * SBCAP;      // 2,007,040
    float* base   = (float*)d_ws;
    int*   flags  = (int*)base;                    // 64
    float* wp1    = base + 64;                     // 4096
    float* bp1    = wp1 + 4096;                    // 128
    float* wp2    = bp1 + 128;                     // 2048
    float* bp2    = wp2 + 2048;                    // 64
    float* woF    = bp2 + 64;                      // 64
    int*   curSB  = (int*)(woF + 64);              // 256
    int*   rowbeg = curSB + 256;                   // N_NODES
    int*   rowend = rowbeg + N_NODES;              // N_NODES
    float* uni    = (float*)(rowend + N_NODES);    // union start
    uint*  pairsSB = (uint*)uni;                   // SBTOT uints (8 MB, alias q)
    float* q      = uni;                           // ND
    float* s      = uni + ND;                      // ND
    ushort* kvb   = (ushort*)(uni + 2 * ND);       // 2*ND ushorts = ND floats
    float* embF   = uni + 3 * ND;                  // ND (aliased with h1)
    float* h1     = embF;
    int*   esrc   = (int*)(uni + 4 * ND);          // SBTOT ints (8 MB)
    // total ~ 60 MB

    const int B = 256;
    const int gCast   = (N_NODES * 32 + B - 1) / B;
    const int gNL32   = (N_NODES + 31) / 32;      // NPB=32
    const int gNL16   = (N_NODES + 63) / 64;      // NPB=64
    const int gGat32  = ((N_NODES + 3) / 4 * 64 + B - 1) / B;
    const int gGat16  = ((N_NODES + 7) / 8 * 64 + B - 1) / B;
    const int gRadA   = (N_EDGES_C + RND - 1) / RND;   // 391

    detect_kernel<<<1, 64, 0, stream>>>(emb, ei, flags);
    cast_emb<<<gCast, B, 0, stream>>>(emb, flags, embF, N_NODES * 32);
    cast_params<<<1, B, 0, stream>>>(Wq1, bq1, Wk1, bk1, Wv1, bv1, Ws1, bs1,
                                     Wq2, bq2, Wk2, bk2, Wv2, bv2, Ws2, bs2,
                                     Wo, bo, flags, wp1, bp1, wp2, bp2, woF);

    // ---- CSR build via LDS-coalesced 2-level radix (shared by both layers) ----
    zero_i<<<1, B, 0, stream>>>(curSB, 256);
    radix_a<<<gRadA, B, 0, stream>>>(ei, flags, curSB, pairsSB);
    radix_b<<<NSB, B, 0, stream>>>(curSB, pairsSB, esrc, rowbeg, rowend);

    // ---- Layer 1 (32 -> 32) ----
    node_linear_f32<32><<<gNL32, B, 0, stream>>>(embF, wp1, bp1, q, kvb, s);
    gather_attn<32, false><<<gGat32, B, 0, stream>>>(
        rowbeg, rowend, esrc, q, kvb, s, woF, flags, h1, nullptr);

    // ---- Layer 2 (32 -> 16) + output linear ----
    node_linear_f32<16><<<gNL16, B, 0, stream>>>(h1, wp2, bp2, q, kvb, s);
    gather_attn<16, true><<<gGat16, B, 0, stream>>>(
        rowbeg, rowend, esrc, q, kvb, s, woF, flags, nullptr, d_out);
}